// Round 13
// baseline (880.375 us; speedup 1.0000x reference)
//
#include <hip/hip_runtime.h>
#include <hip/hip_bf16.h>

#define B_ 16
#define L_ 128
#define G4 80   // 4*H gates
#define AP 40   // padded LDS half-stride

typedef _Float16 half8 __attribute__((ext_vector_type(8)));
typedef float floatx4 __attribute__((ext_vector_type(4)));

__device__ __forceinline__ float bf2f(const __hip_bfloat16 x){ return __bfloat162float(x); }

// dtype-flexible load: isbf=1 -> bf16, isbf=0 -> fp32  (OUT of hot loops only!)
__device__ __forceinline__ float ldw(const void* p, size_t i, int isbf){
  return isbf ? __bfloat162float(((const __hip_bfloat16*)p)[i])
              : ((const float*)p)[i];
}

__device__ __forceinline__ unsigned pack2(_Float16 a, _Float16 b){
  union{ _Float16 h[2]; unsigned u; } z; z.h[0]=a; z.h[1]=b; return z.u;
}

// fast sigmoid/tanh (v_exp + v_rcp; ~1e-6 rel err, inside accuracy budget)
__device__ __forceinline__ float sigf(float x){
  return __builtin_amdgcn_rcpf(1.f + __expf(-x));
}
__device__ __forceinline__ float tanhf_fast(float x){
  float e = __expf(2.f*x);
  return (e - 1.f) * __builtin_amdgcn_rcpf(e + 1.f);
}

// ---------------- diagnostic fill ----------------
__global__ __launch_bounds__(256) void fill_k(float* out, float v){
  int i = blockIdx.x*256 + threadIdx.x;
  if (i < 2048) out[i] = v;
}

// ---------------- input dtype detection ----------------
__global__ __launch_bounds__(256) void detect_k(const void* w, int n, int* flag){
  int t = threadIdx.x;
  const __hip_bfloat16* hb = (const __hip_bfloat16*)w;
  int bad = 0;
  for (int i=t; i<n; i+=256){
    float v = fabsf(bf2f(hb[i]));
    if (!(v < 16.f) || (v != 0.f && v < 1e-5f)) bad++;
  }
  __shared__ int s[256];
  s[t] = bad; __syncthreads();
  for (int k=128;k>0;k>>=1){ if (t<k) s[t]+=s[t+k]; __syncthreads(); }
  if (t==0) *flag = (s[0]*4 > n) ? 0 : 1;
}

// ---------------- augment ----------------
__global__ __launch_bounds__(64) void augment_k(
    const void* __restrict__ inp,
    const void* __restrict__ w1, const void* __restrict__ b1,
    const void* __restrict__ w2, const void* __restrict__ b2,
    float* __restrict__ a, const int* __restrict__ flag)
{
  const int isbf = *flag;
  int pos = blockIdx.x; int t = threadIdx.x;
  __shared__ float xin[20]; __shared__ float hsh[64];
  if (t < 20) xin[t] = ldw(inp, pos*20 + t, isbf);
  __syncthreads();
  float acc = ldw(b1, t, isbf);
  #pragma unroll
  for (int k=0;k<20;++k) acc = fmaf(ldw(w1, t*20+k, isbf), xin[k], acc);
  hsh[t] = fmaxf(acc, 0.f);
  __syncthreads();
  float* arow = a + pos*29;
  if (t < 8){
    float s = ldw(b2, t, isbf);
    #pragma unroll
    for (int k=0;k<64;++k) s = fmaf(ldw(w2, t*64+k, isbf), hsh[k], s);
    arow[21+t] = s;
  }
  if (t == 0) arow[0] = (float)((pos & (L_-1)) * (1.0/127.0));
  if (t < 20) arow[1+t] = xin[t];
}

// ---------------- streamed depth-3 signature (stats + optional materialize, padded stride) ----------------
template<int C, int NS, bool WRITE_SIG>
__global__ __launch_bounds__(256) void sig_scan(
    const float* __restrict__ path,
    float* __restrict__ sig,
    float* __restrict__ psum, float* __restrict__ psq, int SP)
{
  constexpr int C2 = C*C, C3 = C*C*C, S = C + C2 + C3;
  constexpr int SLICE = (C3 + NS - 1)/NS;
  constexpr int EPT = (SLICE + 255)/256;
  constexpr int QPT = (C2 + 255)/256;
  int b = blockIdx.x / NS, sl = blockIdx.x - b*NS;
  int t = threadIdx.x;
  __shared__ float ds[C]; __shared__ float s1s[C];
  __shared__ float s2s[C2]; __shared__ float Qs[C2];
  __shared__ float xprev[C];
  float v[EPT], vs[EPT], vq[EPT];
  int qidx[EPT], kidx[EPT]; bool ok[EPT];
  const int lin0 = sl*SLICE;
  const int lend = min(lin0 + SLICE, C3);
  #pragma unroll
  for (int e=0;e<EPT;++e){
    int lin = lin0 + e*256 + t;
    ok[e] = lin < lend;
    int q = (lin < C3) ? lin / C : 0;
    qidx[e] = q; kidx[e] = (lin < C3) ? (lin - q*C) : 0;
    v[e]=0.f; vs[e]=0.f; vq[e]=0.f;
  }
  float sm1=0.f, sq1=0.f;
  float sm2[QPT], sq2[QPT];
  #pragma unroll
  for (int qq=0;qq<QPT;++qq){ sm2[qq]=0.f; sq2[qq]=0.f; }
  for (int i=t;i<C2;i+=256) s2s[i]=0.f;
  if (t < C){ s1s[t]=0.f; xprev[t]=0.f; }
  const float* prow = path + (size_t)b*L_*C;
  float* srow0 = WRITE_SIG ? (sig + (size_t)b*L_*SP) : nullptr;
  const bool wr = (sl == 0);
  for (int l=0;l<L_;++l){
    __syncthreads();
    if (t < C){ float xv = prow[l*C + t]; ds[t] = xv - xprev[t]; xprev[t] = xv; }
    __syncthreads();
    float* srow = WRITE_SIG ? (srow0 + (size_t)l*SP) : nullptr;
    #pragma unroll
    for (int qq=0;qq<QPT;++qq){
      int q = t + qq*256;
      if (q < C2){
        int i = q / C; int j = q - i*C;
        float di = ds[i], dj = ds[j], s1i = s1s[i], s2v = s2s[q];
        Qs[q] = fmaf(dj, fmaf(di, (1.f/6.f), 0.5f*s1i), s2v);
        float n2 = fmaf(dj, fmaf(di, 0.5f, s1i), s2v);
        s2s[q] = n2;
        if (wr){
          if constexpr (WRITE_SIG) srow[C+q] = n2;
          sm2[qq] += n2; sq2[qq] = fmaf(n2, n2, sq2[qq]);
        }
      }
    }
    __syncthreads();
    #pragma unroll
    for (int e=0;e<EPT;++e){
      if (ok[e]){
        float nv = fmaf(Qs[qidx[e]], ds[kidx[e]], v[e]);
        v[e] = nv;
        if constexpr (WRITE_SIG) srow[C + C2 + lin0 + e*256 + t] = nv;
        vs[e] += nv; vq[e] = fmaf(nv, nv, vq[e]);
      }
    }
    if (t < C){
      float n1 = s1s[t] + ds[t];
      s1s[t] = n1;
      if (wr){
        if constexpr (WRITE_SIG) srow[t] = n1;
        sm1 += n1; sq1 = fmaf(n1, n1, sq1);
      }
    }
  }
  float* psb = psum + (size_t)b*S; float* pqb = psq + (size_t)b*S;
  #pragma unroll
  for (int e=0;e<EPT;++e){
    if (ok[e]){
      int c = C + C2 + lin0 + e*256 + t;
      psb[c] = vs[e]; pqb[c] = vq[e];
    }
  }
  if (wr){
    #pragma unroll
    for (int qq=0;qq<QPT;++qq){ int q = t + qq*256; if (q < C2){ psb[C+q]=sm2[qq]; pqb[C+q]=sq2[qq]; } }
    if (t < C){ psb[t]=sm1; pqb[t]=sq1; }
  }
}

// ---------------- resumable chunked signature scan (compact fallback path) ----------------
template<int C, int NS, int CH>
__global__ __launch_bounds__(256) void sig_chunk(
    const float* __restrict__ path,
    float* __restrict__ chk,
    float* __restrict__ st3, float* __restrict__ st2,
    float* __restrict__ st1, float* __restrict__ stx,
    int lc)
{
  constexpr int C2 = C*C, C3 = C*C*C, S = C + C2 + C3;
  constexpr int SLICE = (C3 + NS - 1)/NS;
  constexpr int EPT = (SLICE + 255)/256;
  constexpr int QPT = (C2 + 255)/256;
  int b = blockIdx.x / NS, sl = blockIdx.x - b*NS;
  int t = threadIdx.x;
  __shared__ float ds[C]; __shared__ float s1s[C];
  __shared__ float s2s[C2]; __shared__ float Qs[C2];
  __shared__ float xprev[C];
  float v[EPT];
  int qidx[EPT], kidx[EPT]; bool ok[EPT];
  const int lin0 = sl*SLICE;
  const int lend = min(lin0 + SLICE, C3);
  #pragma unroll
  for (int e=0;e<EPT;++e){
    int lin = lin0 + e*256 + t;
    ok[e] = lin < lend;
    int q = (lin < C3) ? lin / C : 0;
    qidx[e] = q; kidx[e] = (lin < C3) ? (lin - q*C) : 0;
  }
  if (lc == 0){
    #pragma unroll
    for (int e=0;e<EPT;++e) v[e] = 0.f;
    for (int i=t;i<C2;i+=256) s2s[i] = 0.f;
    if (t < C){ s1s[t]=0.f; xprev[t]=0.f; }
  } else {
    #pragma unroll
    for (int e=0;e<EPT;++e) v[e] = ok[e] ? st3[(size_t)b*C3 + lin0 + e*256 + t] : 0.f;
    for (int i=t;i<C2;i+=256) s2s[i] = st2[(size_t)b*C2 + i];
    if (t < C){ s1s[t] = st1[b*C + t]; xprev[t] = stx[b*C + t]; }
  }
  const float* prow = path + (size_t)b*L_*C;
  const bool wr = (sl == 0);
  for (int il=0; il<CH; ++il){
    int l = lc*CH + il;
    __syncthreads();
    if (t < C){ float xv = prow[l*C + t]; ds[t] = xv - xprev[t]; xprev[t] = xv; }
    __syncthreads();
    float* crow = chk + ((size_t)(b*CH + il))*S;
    #pragma unroll
    for (int qq=0;qq<QPT;++qq){
      int q = t + qq*256;
      if (q < C2){
        int i = q / C; int j = q - i*C;
        float di = ds[i], dj = ds[j], s1i = s1s[i], s2v = s2s[q];
        Qs[q] = fmaf(dj, fmaf(di, (1.f/6.f), 0.5f*s1i), s2v);
        float n2 = fmaf(dj, fmaf(di, 0.5f, s1i), s2v);
        s2s[q] = n2;
        if (wr) crow[C+q] = n2;
      }
    }
    __syncthreads();
    #pragma unroll
    for (int e=0;e<EPT;++e){
      if (ok[e]){
        float nv = fmaf(Qs[qidx[e]], ds[kidx[e]], v[e]);
        v[e] = nv;
        crow[C + C2 + lin0 + e*256 + t] = nv;
      }
    }
    if (t < C){
      float n1 = s1s[t] + ds[t];
      s1s[t] = n1;
      if (wr) crow[t] = n1;
    }
  }
  #pragma unroll
  for (int e=0;e<EPT;++e) if (ok[e]) st3[(size_t)b*C3 + lin0 + e*256 + t] = v[e];
  if (wr){
    __syncthreads();
    for (int i=t;i<C2;i+=256) st2[(size_t)b*C2 + i] = s2s[i];
    if (t < C){ st1[b*C + t] = s1s[t]; stx[b*C + t] = xprev[t]; }
  }
}

// ---------------- batchnorm stats (zero-pads mu/inv to KP) ----------------
__global__ __launch_bounds__(256) void bn_stats(
    const float* __restrict__ psum, const float* __restrict__ psq,
    float* __restrict__ mu, float* __restrict__ inv, int S, int KP, float invN)
{
  int c = blockIdx.x*256 + threadIdx.x;
  if (c >= KP) return;
  if (c >= S){ mu[c] = 0.f; inv[c] = 0.f; return; }
  float s = 0.f, q = 0.f;
  for (int b=0;b<B_;++b){ s += psum[(size_t)b*S + c]; q += psq[(size_t)b*S + c]; }
  float m = s * invN;
  float var = fmaxf(fmaf(q, invN, -m*m), 0.f);
  mu[c] = m;
  inv[c] = 1.f / sqrtf(var + 1e-5f);
}

// ---------------- W-prep: pack 256*W (NO inv — A is normalized in gemm!) ----------------
__global__ __launch_bounds__(256) void wprep_k(
    const void* __restrict__ W,
    _Float16* __restrict__ whi, _Float16* __restrict__ wlo,
    int K, int nT, const int* __restrict__ flag)
{
  const int isbf = *flag;
  int idx = blockIdx.x*256 + threadIdx.x;
  if (idx >= nT*320) return;
  int kt = idx / 320; int rem = idx - kt*320;
  int j = rem >> 2, cg = (rem & 3) << 3;
  unsigned uh[4], ul[4];
  #pragma unroll
  for (int e=0;e<8;e+=2){
    int c0 = kt*32 + cg + e, c1 = c0 + 1;
    float w0 = (c0 < K) ? 256.f*ldw(W, (size_t)j*K + c0, isbf) : 0.f;
    float w1 = (c1 < K) ? 256.f*ldw(W, (size_t)j*K + c1, isbf) : 0.f;
    _Float16 h0 = (_Float16)w0, h1 = (_Float16)w1;
    _Float16 l0 = (_Float16)(w0 - (float)h0), l1 = (_Float16)(w1 - (float)h1);
    uh[e>>1] = pack2(h0, h1); ul[e>>1] = pack2(l0, l1);
  }
  uint4 vh; vh.x=uh[0]; vh.y=uh[1]; vh.z=uh[2]; vh.w=uh[3];
  uint4 vl; vl.x=ul[0]; vl.y=ul[1]; vl.z=ul[2]; vl.w=ul[3];
  size_t base = ((size_t)kt*80 + j)*32 + cg;
  *(uint4*)&whi[base] = vh;
  *(uint4*)&wlo[base] = vl;
}

// ---------------- MFMA GEMM v2: normalized A (fp16 hi/lo), packed 256*W B ----------------
__global__ __launch_bounds__(256) void gemm_mfma(
    const float* __restrict__ X, const float* __restrict__ mu, const float* __restrict__ inv,
    const _Float16* __restrict__ whi, const _Float16* __restrict__ wlo,
    float* __restrict__ part, int SP, int nT, int tpc)
{
  __shared__ _Float16 Ah[64][AP];
  __shared__ _Float16 Al[64][AP];
  __shared__ _Float16 Bh[80][AP];
  __shared__ _Float16 Bl[80][AP];
  int t = threadIdx.x;
  int mb = blockIdx.x, ks = blockIdx.y;
  int m0 = mb*64;
  int kt0 = ks*tpc, kt1 = min(kt0 + tpc, nT);
  int lane = t & 63, w = t >> 6;
  int ln = lane & 15, quad = lane >> 4;
  int q8 = quad*8;
  int ar = t >> 2, acg = (t & 3) << 3;
  const float* arow_p = X + (size_t)(m0 + ar)*SP + acg;

  floatx4 acc[5];
  #pragma unroll
  for (int nt=0; nt<5; ++nt) acc[nt] = (floatx4){0.f,0.f,0.f,0.f};

  float4 pf0, pf1, pm0, pm1, pv0, pv1;
  if (kt0 < kt1){
    int kb = kt0 << 5;
    pf0 = *(const float4*)(arow_p + kb);
    pf1 = *(const float4*)(arow_p + kb + 4);
    pm0 = *(const float4*)(mu + kb + acg);
    pm1 = *(const float4*)(mu + kb + acg + 4);
    pv0 = *(const float4*)(inv + kb + acg);
    pv1 = *(const float4*)(inv + kb + acg + 4);
  }

  for (int kt=kt0; kt<kt1; ++kt){
    __syncthreads();
    {
      float xv[8], mv[8], iv[8];
      *(float4*)&xv[0] = pf0; *(float4*)&xv[4] = pf1;
      *(float4*)&mv[0] = pm0; *(float4*)&mv[4] = pm1;
      *(float4*)&iv[0] = pv0; *(float4*)&iv[4] = pv1;
      unsigned uh[4], ul[4];
      #pragma unroll
      for (int e=0; e<8; e+=2){
        float n0 = (xv[e]   - mv[e])   * iv[e];
        float n1 = (xv[e+1] - mv[e+1]) * iv[e+1];
        _Float16 h0 = (_Float16)n0, h1 = (_Float16)n1;
        _Float16 l0 = (_Float16)(n0 - (float)h0), l1 = (_Float16)(n1 - (float)h1);
        uh[e>>1] = pack2(h0, h1); ul[e>>1] = pack2(l0, l1);
      }
      uint4 vh; vh.x=uh[0]; vh.y=uh[1]; vh.z=uh[2]; vh.w=uh[3];
      uint4 vl; vl.x=ul[0]; vl.y=ul[1]; vl.z=ul[2]; vl.w=ul[3];
      *(uint4*)&Ah[ar][acg] = vh;
      *(uint4*)&Al[ar][acg] = vl;
    }
    {
      const _Float16* bh = whi + (size_t)kt*80*32;
      const _Float16* bl = wlo + (size_t)kt*80*32;
      #pragma unroll
      for (int it=0; it<2; ++it){
        int idx = it*256 + t;
        if (idx < 320){
          int j = idx >> 2, cg = (idx & 3) << 3;
          *(uint4*)&Bh[j][cg] = *(const uint4*)(bh + j*32 + cg);
          *(uint4*)&Bl[j][cg] = *(const uint4*)(bl + j*32 + cg);
        }
      }
    }
    __syncthreads();
    if (kt+1 < kt1){
      int kb = (kt+1) << 5;
      pf0 = *(const float4*)(arow_p + kb);
      pf1 = *(const float4*)(arow_p + kb + 4);
      pm0 = *(const float4*)(mu + kb + acg);
      pm1 = *(const float4*)(mu + kb + acg + 4);
      pv0 = *(const float4*)(inv + kb + acg);
      pv1 = *(const float4*)(inv + kb + acg + 4);
    }
    half8 ah = *(const half8*)&Ah[w*16 + ln][q8];
    half8 al = *(const half8*)&Al[w*16 + ln][q8];
    half8 bh[5], bl[5];
    #pragma unroll
    for (int nt=0; nt<5; ++nt){
      bh[nt] = *(const half8*)&Bh[nt*16 + ln][q8];
      bl[nt] = *(const half8*)&Bl[nt*16 + ln][q8];
    }
    #pragma unroll
    for (int nt=0; nt<5; ++nt){
      acc[nt] = __builtin_amdgcn_mfma_f32_16x16x32_f16(ah, bh[nt], acc[nt], 0, 0, 0);
      acc[nt] = __builtin_amdgcn_mfma_f32_16x16x32_f16(al, bh[nt], acc[nt], 0, 0, 0);
      acc[nt] = __builtin_amdgcn_mfma_f32_16x16x32_f16(ah, bl[nt], acc[nt], 0, 0, 0);
    }
  }
  float* pb = part + (size_t)ks*2048*80;
  #pragma unroll
  for (int nt=0; nt<5; ++nt)
    #pragma unroll
    for (int r=0; r<4; ++r){
      int m = m0 + w*16 + quad*4 + r;
      int n = nt*16 + ln;
      pb[(size_t)m*80 + n] = acc[nt][r];
    }
}

// ---------------- fp32 fallback GEMM (compact path) ----------------
__global__ __launch_bounds__(256) void gemm_bn(
    const float* __restrict__ X, const float* __restrict__ mu, const float* __restrict__ inv,
    const void* __restrict__ W,
    float* __restrict__ part, int K, int tpc, const int* __restrict__ flag, int prows)
{
  const int isbf = *flag;
  int mb = blockIdx.x, ks = blockIdx.y;
  int nT = (K + 31) >> 5;
  int kt0 = ks*tpc, kt1 = min(kt0 + tpc, nT);
  __shared__ __align__(16) float xs[32][132];
  __shared__ float wsm[32][84];
  int t = threadIdx.x;
  int tm = t & 15, tj = t >> 4;
  int m0 = mb*128;
  float acc[8][5];
  #pragma unroll
  for (int i=0;i<8;++i)
    #pragma unroll
    for (int j5=0;j5<5;++j5) acc[i][j5] = 0.f;
  int cx = t & 31, rx = t >> 5;
  for (int kt=kt0; kt<kt1; ++kt){
    int kb = kt << 5;
    __syncthreads();
    int c = kb + cx;
    bool cv = c < K;
    float m  = cv ? mu[c]  : 0.f;
    float iv = cv ? inv[c] : 0.f;
    #pragma unroll
    for (int i=0;i<16;++i){
      int row = i*8 + rx;
      float xv = cv ? X[(size_t)(m0+row)*K + c] : 0.f;
      xs[cx][row] = (xv - m) * iv;
    }
    #pragma unroll
    for (int i=0;i<10;++i){
      int row = i*8 + rx;
      wsm[cx][row] = cv ? ldw(W, (size_t)row*K + c, isbf) : 0.f;
    }
    __syncthreads();
    #pragma unroll 2
    for (int kk=0;kk<32;++kk){
      float xv[8]; float wv[5];
      *(float4*)&xv[0] = *(const float4*)&xs[kk][tm*8];
      *(float4*)&xv[4] = *(const float4*)&xs[kk][tm*8+4];
      #pragma unroll
      for (int j5=0;j5<5;++j5) wv[j5] = wsm[kk][tj + j5*16];
      #pragma unroll
      for (int i=0;i<8;++i)
        #pragma unroll
        for (int j5=0;j5<5;++j5)
          acc[i][j5] = fmaf(xv[i], wv[j5], acc[i][j5]);
    }
  }
  float* pb = part + (size_t)ks*prows*80;
  #pragma unroll
  for (int i=0;i<8;++i){
    int m = m0 + tm*8 + i;
    #pragma unroll
    for (int j5=0;j5<5;++j5)
      pb[(size_t)m*80 + tj + j5*16] = acc[i][j5];
  }
}

// ---------------- reduce partials + layer0 biases (big path; scale 1/256) ----------------
__global__ __launch_bounds__(256) void greduce(
    const float* __restrict__ part,
    const void* __restrict__ bih, const void* __restrict__ bhh,
    float* __restrict__ G, int KS, const int* __restrict__ flag, float scale)
{
  const int isbf = *flag;
  int idx = blockIdx.x*256 + threadIdx.x;
  if (idx >= 2048*80) return;
  int j = idx % 80;
  float s = 0.f;
  for (int k=0;k<KS;++k) s += part[(size_t)k*2048*80 + idx];
  G[idx] = fmaf(s, scale, ldw(bih, j, isbf) + ldw(bhh, j, isbf));
}

// ---------------- reduce chunk partials (compact path) ----------------
template<int CH>
__global__ __launch_bounds__(256) void greduce_chunk(
    const float* __restrict__ part,
    const void* __restrict__ bih, const void* __restrict__ bhh,
    float* __restrict__ G, int KS, const int* __restrict__ flag, int lc)
{
  const int isbf = *flag;
  int idx = blockIdx.x*256 + threadIdx.x;
  if (idx >= B_*CH*80) return;
  int j = idx % 80;
  int rc = idx / 80;
  int b = rc / CH, il = rc % CH;
  float s = ldw(bih, j, isbf) + ldw(bhh, j, isbf);
  for (int k=0;k<KS;++k) s += part[(size_t)k*B_*CH*80 + idx];
  G[((size_t)b*L_ + lc*CH + il)*80 + j] = s;
}

// ---------------- pipelined single-wave 2-layer LSTM ----------------
// 1 wave/batch. Half A (lanes 0-31) computes layer0 of step i while half B
// (lanes 32-63) computes layer1 of step i-1 — both depend only on h0(i-1),
// h1(i-2), so they run in the SAME instructions (uniform code, per-half
// operands). One dot stage + one act stage + one broadcast stage per step
// (vs 4 cross-lane stages in the unpipelined version).
__global__ __launch_bounds__(64) void lstm2_pipe(
    const float* __restrict__ G0,
    const void* __restrict__ whh0,
    const void* __restrict__ wih1,
    const void* __restrict__ whh1,
    const void* __restrict__ bih1,
    const void* __restrict__ bhh1,
    float* __restrict__ oseq,
    float* __restrict__ dout,
    const void* __restrict__ linw,
    const void* __restrict__ linb,
    const int* __restrict__ flag)
{
  const int isbf = *flag;
  int b = blockIdx.x; int t = threadIdx.x;
  int half = t >> 5, k0 = t & 31;
  int k = (k0 < 20) ? k0 : 19;          // clamp idle lanes (never stored/shfl-read)
  __shared__ float wsh[3*1600];
  if (isbf){
    const __hip_bfloat16* s0 = (const __hip_bfloat16*)whh0;
    const __hip_bfloat16* s1 = (const __hip_bfloat16*)wih1;
    const __hip_bfloat16* s2 = (const __hip_bfloat16*)whh1;
    for (int i=t;i<1600;i+=64){
      wsh[i] = bf2f(s0[i]); wsh[1600+i] = bf2f(s1[i]); wsh[3200+i] = bf2f(s2[i]);
    }
  } else {
    const float* s0 = (const float*)whh0;
    const float* s1 = (const float*)wih1;
    const float* s2 = (const float*)whh1;
    for (int i=t;i<1600;i+=64){
      wsh[i] = s0[i]; wsh[1600+i] = s1[i]; wsh[3200+i] = s2[i];
    }
  }
  __syncthreads();                       // once, before the scan
  // per-half weight selection: A: wA=Whh0, wB=0 ; B: wA=W1i, wB=W1h
  float wA[4][20], wB[4][20];
  int offA = half ? 1600 : 0;
  #pragma unroll
  for (int q=0;q<4;++q)
    #pragma unroll
    for (int j=0;j<20;++j){
      int row = q*20 + k;
      wA[q][j] = wsh[offA + row*20 + j];
      wB[q][j] = half ? wsh[3200 + row*20 + j] : 0.f;
    }
  float bias1[4];
  #pragma unroll
  for (int q=0;q<4;++q)
    bias1[q] = half ? (ldw(bih1, q*20+k, isbf) + ldw(bhh1, q*20+k, isbf)) : 0.f;
  float lw20[20]; float lb = 0.f;
  const bool fin = (dout != nullptr);
  if (fin){
    #pragma unroll
    for (int j=0;j<20;++j) lw20[j] = ldw(linw, j, isbf);
    lb = ldw(linb, 0, isbf);
  }
  float h0r[20], h1r[20];
  #pragma unroll
  for (int j=0;j<20;++j){ h0r[j]=0.f; h1r[j]=0.f; }
  float c = 0.f;                         // A lanes: c0 ; B lanes: c1
  const float* Gb = G0 + (size_t)b*L_*G4;
  float gc[4], gn[4];
  #pragma unroll
  for (int q=0;q<4;++q) gc[q] = Gb[q*20 + k];
  for (int i=0; i<=L_; ++i){
    int nx = (i+1 < L_) ? (i+1) : (L_-1);
    #pragma unroll
    for (int q=0;q<4;++q) gn[q] = Gb[nx*G4 + q*20 + k];
    // ---- unified gate dots (A: layer0 step i ; B: layer1 step i-1) ----
    float s[4];
    #pragma unroll
    for (int q=0;q<4;++q){
      float v = half ? bias1[q] : gc[q];
      #pragma unroll
      for (int j=0;j<20;++j) v = fmaf(wA[q][j], h0r[j], v);
      #pragma unroll
      for (int j=0;j<20;++j) v = fmaf(wB[q][j], h1r[j], v);
      s[q] = v;
    }
    float ig = sigf(s[0]), fg = sigf(s[1]);
    float gg = tanhf_fast(s[2]), og = sigf(s[3]);
    bool valid = half ? (i > 0) : (i < L_);
    float cn = fmaf(fg, c, ig*gg);
    float hn = og * tanhf_fast(cn);
    c  = valid ? cn : c;
    hn = valid ? hn : 0.f;
    if (oseq && half==1 && k0 < 20 && i >= 1)
      oseq[((size_t)b*L_ + (i-1))*20 + k] = hn;
    // ---- broadcast: h0 from half A, h1 from half B ----
    #pragma unroll
    for (int j=0;j<20;++j) h0r[j] = __shfl(hn, j);
    #pragma unroll
    for (int j=0;j<20;++j) h1r[j] = __shfl(hn, 32+j);
    if (fin && i >= 1){
      float p = lb;
      #pragma unroll
      for (int j=0;j<20;++j){
        float h = h1r[j];
        float wv = (h >= 0.f) ? h : 0.01f*h;   // LeakyReLU(0.01)
        p = fmaf(lw20[j], wv, p);
      }
      if (t == 0) dout[b*L_ + (i-1)] = p;
    }
    #pragma unroll
    for (int q=0;q<4;++q) gc[q] = gn[q];
  }
}

extern "C" void kernel_launch(void* const* d_in, const int* in_sizes, int n_in,
                              void* d_out, int out_size, void* d_ws, size_t ws_size,
                              hipStream_t stream)
{
  (void)out_size;
  auto P = [&](int i){ return (const void*)d_in[i]; };
  float* dout = (float*)d_out;

  static const int EXP[31] = {40960,1280,64,512,8,
    2020720,1600,80,80,1600,1600,80,80,
    673600,1600,80,80,1600,1600,80,80,
    673600,1600,80,80,1600,1600,80,80,
    20,1};
  int bad = (n_in == 31) ? -1 : 99;
  if (bad < 0) for (int i=0;i<31;++i) if (in_sizes[i] != EXP[i]){ bad = i; break; }
  if (bad >= 0){
    fill_k<<<dim3(8), dim3(256), 0, stream>>>(dout, 1000.f + (float)bad);
    return;
  }

  constexpr int CH = 16, NCH = L_/CH;
  const int S1 = 25259, S2 = 8420;
  const int nT1 = (S1+31)/32, nT2 = (S2+31)/32;   // 790, 264
  const int KP1 = nT1*32, KP2 = nT2*32;           // 25280, 8448
  const int SP1 = 25280, SP2 = 8420;

  float* ws = (float*)d_ws;
  size_t off = 0;
  auto alloc = [&](size_t n){ float* p = ws + off; off += (n+3)&~(size_t)3; return p; };
  float* a    = alloc(2048*29);
  float* o1   = alloc(2048*20);
  float* o2   = alloc(2048*20);
  float* mu   = alloc(KP1);
  float* inv  = alloc(KP1);
  float* psum = alloc((size_t)B_*S1);
  float* psq  = alloc((size_t)B_*S1);
  float* G    = alloc(2048*80);
  int*   flag = (int*)alloc(64);

  const bool big     = ws_size >= (size_t)234*1000*1000;
  const bool compact = ws_size >= (size_t)58*1000*1000;
  if (!big && !compact){
    float mb = (float)(ws_size / (1024.0*1024.0));
    fill_k<<<dim3(8), dim3(256), 0, stream>>>(dout, 4000.f + mb);
    return;
  }

  detect_k<<<dim3(1), dim3(256), 0, stream>>>(P(1), 1280, flag);
  augment_k<<<dim3(2048), dim3(64), 0, stream>>>(P(0), P(1), P(2), P(3), P(4), a, flag);

  if (big){
    const int KS = 16;
    float* part = alloc((size_t)KS*2048*80);
    float* whif = alloc((size_t)nT1*1280);
    float* wlof = alloc((size_t)nT1*1280);
    float* sigb = alloc((size_t)2048*SP1);
    _Float16* whi = (_Float16*)whif;
    _Float16* wlo = (_Float16*)wlof;
    const int tpc1 = (nT1 + KS-1)/KS;
    const int tpc2 = (nT2 + KS-1)/KS;
    const float sc = 1.f/256.f;

    auto big_stage = [&](const float* x, int S, int KP, int SP, int nT, int tpc,
                         int wih0_i, int bih0_i, int bhh0_i, int whh0_i,
                         int wih1_i, int whh1_i, int bih1_i, int bhh1_i,
                         float* oseq, float* dd, int lw_i, int lb_i, bool c29)
    {
      if (c29) sig_scan<29,64,true><<<dim3(B_*64), dim3(256), 0, stream>>>(x, sigb, psum, psq, SP);
      else     sig_scan<20,32,true><<<dim3(B_*32), dim3(256), 0, stream>>>(x, sigb, psum, psq, SP);
      bn_stats<<<dim3((KP+255)/256), dim3(256), 0, stream>>>(psum, psq, mu, inv, S, KP, 1.f/2048.f);
      wprep_k<<<dim3((nT*320+255)/256), dim3(256), 0, stream>>>(P(wih0_i), whi, wlo, S, nT, flag);
      gemm_mfma<<<dim3(32, KS), dim3(256), 0, stream>>>(sigb, mu, inv, whi, wlo, part, SP, nT, tpc);
      greduce<<<dim3(640), dim3(256), 0, stream>>>(part, P(bih0_i), P(bhh0_i), G, KS, flag, sc);
      lstm2_pipe<<<dim3(B_), dim3(64), 0, stream>>>(G, P(whh0_i), P(wih1_i), P(whh1_i), P(bih1_i), P(bhh1_i),
                                                    oseq, dd,
                                                    lw_i >= 0 ? P(lw_i) : nullptr,
                                                    lb_i >= 0 ? P(lb_i) : nullptr, flag);
    };

    big_stage(a,  S1, KP1, SP1, nT1, tpc1,  5, 7, 8, 6,  9,10,11,12, o1, nullptr, -1, -1, true);
    big_stage(o1, S2, KP2, SP2, nT2, tpc2, 13,15,16,14, 17,18,19,20, o2, nullptr, -1, -1, false);
    big_stage(o2, S2, KP2, SP2, nT2, tpc2, 21,23,24,22, 25,26,27,28, nullptr, dout, 29, 30, false);
  } else {
    float* st3  = alloc((size_t)B_*29*29*29);
    float* st2  = alloc((size_t)B_*29*29);
    float* st1  = alloc((size_t)B_*29);
    float* stx  = alloc((size_t)B_*29);
    const int KSC = 128;
    float* part = alloc((size_t)KSC*B_*CH*80);
    float* chk  = alloc((size_t)B_*CH*S1);
    const int tpc1 = (nT1 + KSC-1)/KSC;
    const int tpc2 = (nT2 + KSC-1)/KSC;
    const int GRED = (B_*CH*80 + 255)/256;

    sig_scan<29,64,false><<<dim3(B_*64), dim3(256), 0, stream>>>(a, nullptr, psum, psq, S1);
    bn_stats<<<dim3((KP1+255)/256), dim3(256), 0, stream>>>(psum, psq, mu, inv, S1, KP1, 1.f/2048.f);
    for (int lc=0; lc<NCH; ++lc){
      sig_chunk<29,16,CH><<<dim3(B_*16), dim3(256), 0, stream>>>(a, chk, st3, st2, st1, stx, lc);
      gemm_bn<<<dim3(2, KSC), dim3(256), 0, stream>>>(chk, mu, inv, P(5), part, S1, tpc1, flag, B_*CH);
      greduce_chunk<CH><<<dim3(GRED), dim3(256), 0, stream>>>(part, P(7), P(8), G, KSC, flag, lc);
    }
    lstm2_pipe<<<dim3(B_), dim3(64), 0, stream>>>(G, P(6), P(9), P(10), P(11), P(12),
                                                  o1, nullptr, nullptr, nullptr, flag);

    sig_scan<20,32,false><<<dim3(B_*32), dim3(256), 0, stream>>>(o1, nullptr, psum, psq, S2);
    bn_stats<<<dim3((KP2+255)/256), dim3(256), 0, stream>>>(psum, psq, mu, inv, S2, KP2, 1.f/2048.f);
    for (int lc=0; lc<NCH; ++lc){
      sig_chunk<20,8,CH><<<dim3(B_*8), dim3(256), 0, stream>>>(o1, chk, st3, st2, st1, stx, lc);
      gemm_bn<<<dim3(2, KSC), dim3(256), 0, stream>>>(chk, mu, inv, P(13), part, S2, tpc2, flag, B_*CH);
      greduce_chunk<CH><<<dim3(GRED), dim3(256), 0, stream>>>(part, P(15), P(16), G, KSC, flag, lc);
    }
    lstm2_pipe<<<dim3(B_), dim3(64), 0, stream>>>(G, P(14), P(17), P(18), P(19), P(20),
                                                  o2, nullptr, nullptr, nullptr, flag);

    sig_scan<20,32,false><<<dim3(B_*32), dim3(256), 0, stream>>>(o2, nullptr, psum, psq, S2);
    bn_stats<<<dim3((KP2+255)/256), dim3(256), 0, stream>>>(psum, psq, mu, inv, S2, KP2, 1.f/2048.f);
    for (int lc=0; lc<NCH; ++lc){
      sig_chunk<20,8,CH><<<dim3(B_*8), dim3(256), 0, stream>>>(o2, chk, st3, st2, st1, stx, lc);
      gemm_bn<<<dim3(2, KSC), dim3(256), 0, stream>>>(chk, mu, inv, P(21), part, S2, tpc2, flag, B_*CH);
      greduce_chunk<CH><<<dim3(GRED), dim3(256), 0, stream>>>(part, P(23), P(24), G, KSC, flag, lc);
    }
    lstm2_pipe<<<dim3(B_), dim3(64), 0, stream>>>(G, P(22), P(25), P(26), P(27), P(28),
                                                  nullptr, dout, P(29), P(30), flag);
  }
}

// Round 14
// 809.573 us; speedup vs baseline: 1.0875x; 1.0875x over previous
//
#include <hip/hip_runtime.h>
#include <hip/hip_bf16.h>

#define B_ 16
#define L_ 128
#define G4 80   // 4*H gates
#define AP 40   // padded LDS half-stride

typedef _Float16 half8 __attribute__((ext_vector_type(8)));
typedef float floatx4 __attribute__((ext_vector_type(4)));

__device__ __forceinline__ float bf2f(const __hip_bfloat16 x){ return __bfloat162float(x); }

// dtype-flexible load: isbf=1 -> bf16, isbf=0 -> fp32  (OUT of hot loops only!)
__device__ __forceinline__ float ldw(const void* p, size_t i, int isbf){
  return isbf ? __bfloat162float(((const __hip_bfloat16*)p)[i])
              : ((const float*)p)[i];
}

__device__ __forceinline__ unsigned pack2(_Float16 a, _Float16 b){
  union{ _Float16 h[2]; unsigned u; } z; z.h[0]=a; z.h[1]=b; return z.u;
}

// fast sigmoid/tanh (v_exp + v_rcp; ~1e-6 rel err, inside accuracy budget)
__device__ __forceinline__ float sigf(float x){
  return __builtin_amdgcn_rcpf(1.f + __expf(-x));
}
__device__ __forceinline__ float tanhf_fast(float x){
  float e = __expf(2.f*x);
  return (e - 1.f) * __builtin_amdgcn_rcpf(e + 1.f);
}
// broadcast lane j's value wave-wide via v_readlane (no DS op!)
__device__ __forceinline__ float rdlane(float v, int lane){
  return __int_as_float(__builtin_amdgcn_readlane(__float_as_int(v), lane));
}

// ---------------- diagnostic fill ----------------
__global__ __launch_bounds__(256) void fill_k(float* out, float v){
  int i = blockIdx.x*256 + threadIdx.x;
  if (i < 2048) out[i] = v;
}

// ---------------- input dtype detection ----------------
__global__ __launch_bounds__(256) void detect_k(const void* w, int n, int* flag){
  int t = threadIdx.x;
  const __hip_bfloat16* hb = (const __hip_bfloat16*)w;
  int bad = 0;
  for (int i=t; i<n; i+=256){
    float v = fabsf(bf2f(hb[i]));
    if (!(v < 16.f) || (v != 0.f && v < 1e-5f)) bad++;
  }
  __shared__ int s[256];
  s[t] = bad; __syncthreads();
  for (int k=128;k>0;k>>=1){ if (t<k) s[t]+=s[t+k]; __syncthreads(); }
  if (t==0) *flag = (s[0]*4 > n) ? 0 : 1;
}

// ---------------- augment ----------------
__global__ __launch_bounds__(64) void augment_k(
    const void* __restrict__ inp,
    const void* __restrict__ w1, const void* __restrict__ b1,
    const void* __restrict__ w2, const void* __restrict__ b2,
    float* __restrict__ a, const int* __restrict__ flag)
{
  const int isbf = *flag;
  int pos = blockIdx.x; int t = threadIdx.x;
  __shared__ float xin[20]; __shared__ float hsh[64];
  if (t < 20) xin[t] = ldw(inp, pos*20 + t, isbf);
  __syncthreads();
  float acc = ldw(b1, t, isbf);
  #pragma unroll
  for (int k=0;k<20;++k) acc = fmaf(ldw(w1, t*20+k, isbf), xin[k], acc);
  hsh[t] = fmaxf(acc, 0.f);
  __syncthreads();
  float* arow = a + pos*29;
  if (t < 8){
    float s = ldw(b2, t, isbf);
    #pragma unroll
    for (int k=0;k<64;++k) s = fmaf(ldw(w2, t*64+k, isbf), hsh[k], s);
    arow[21+t] = s;
  }
  if (t == 0) arow[0] = (float)((pos & (L_-1)) * (1.0/127.0));
  if (t < 20) arow[1+t] = xin[t];
}

// ---------------- streamed depth-3 signature (stats + optional materialize, padded stride) ----------------
template<int C, int NS, bool WRITE_SIG>
__global__ __launch_bounds__(256) void sig_scan(
    const float* __restrict__ path,
    float* __restrict__ sig,
    float* __restrict__ psum, float* __restrict__ psq, int SP)
{
  constexpr int C2 = C*C, C3 = C*C*C, S = C + C2 + C3;
  constexpr int SLICE = (C3 + NS - 1)/NS;
  constexpr int EPT = (SLICE + 255)/256;
  constexpr int QPT = (C2 + 255)/256;
  int b = blockIdx.x / NS, sl = blockIdx.x - b*NS;
  int t = threadIdx.x;
  __shared__ float ds[C]; __shared__ float s1s[C];
  __shared__ float s2s[C2]; __shared__ float Qs[C2];
  __shared__ float xprev[C];
  float v[EPT], vs[EPT], vq[EPT];
  int qidx[EPT], kidx[EPT]; bool ok[EPT];
  const int lin0 = sl*SLICE;
  const int lend = min(lin0 + SLICE, C3);
  #pragma unroll
  for (int e=0;e<EPT;++e){
    int lin = lin0 + e*256 + t;
    ok[e] = lin < lend;
    int q = (lin < C3) ? lin / C : 0;
    qidx[e] = q; kidx[e] = (lin < C3) ? (lin - q*C) : 0;
    v[e]=0.f; vs[e]=0.f; vq[e]=0.f;
  }
  float sm1=0.f, sq1=0.f;
  float sm2[QPT], sq2[QPT];
  #pragma unroll
  for (int qq=0;qq<QPT;++qq){ sm2[qq]=0.f; sq2[qq]=0.f; }
  for (int i=t;i<C2;i+=256) s2s[i]=0.f;
  if (t < C){ s1s[t]=0.f; xprev[t]=0.f; }
  const float* prow = path + (size_t)b*L_*C;
  float* srow0 = WRITE_SIG ? (sig + (size_t)b*L_*SP) : nullptr;
  const bool wr = (sl == 0);
  for (int l=0;l<L_;++l){
    __syncthreads();
    if (t < C){ float xv = prow[l*C + t]; ds[t] = xv - xprev[t]; xprev[t] = xv; }
    __syncthreads();
    float* srow = WRITE_SIG ? (srow0 + (size_t)l*SP) : nullptr;
    #pragma unroll
    for (int qq=0;qq<QPT;++qq){
      int q = t + qq*256;
      if (q < C2){
        int i = q / C; int j = q - i*C;
        float di = ds[i], dj = ds[j], s1i = s1s[i], s2v = s2s[q];
        Qs[q] = fmaf(dj, fmaf(di, (1.f/6.f), 0.5f*s1i), s2v);
        float n2 = fmaf(dj, fmaf(di, 0.5f, s1i), s2v);
        s2s[q] = n2;
        if (wr){
          if constexpr (WRITE_SIG) srow[C+q] = n2;
          sm2[qq] += n2; sq2[qq] = fmaf(n2, n2, sq2[qq]);
        }
      }
    }
    __syncthreads();
    #pragma unroll
    for (int e=0;e<EPT;++e){
      if (ok[e]){
        float nv = fmaf(Qs[qidx[e]], ds[kidx[e]], v[e]);
        v[e] = nv;
        if constexpr (WRITE_SIG) srow[C + C2 + lin0 + e*256 + t] = nv;
        vs[e] += nv; vq[e] = fmaf(nv, nv, vq[e]);
      }
    }
    if (t < C){
      float n1 = s1s[t] + ds[t];
      s1s[t] = n1;
      if (wr){
        if constexpr (WRITE_SIG) srow[t] = n1;
        sm1 += n1; sq1 = fmaf(n1, n1, sq1);
      }
    }
  }
  float* psb = psum + (size_t)b*S; float* pqb = psq + (size_t)b*S;
  #pragma unroll
  for (int e=0;e<EPT;++e){
    if (ok[e]){
      int c = C + C2 + lin0 + e*256 + t;
      psb[c] = vs[e]; pqb[c] = vq[e];
    }
  }
  if (wr){
    #pragma unroll
    for (int qq=0;qq<QPT;++qq){ int q = t + qq*256; if (q < C2){ psb[C+q]=sm2[qq]; pqb[C+q]=sq2[qq]; } }
    if (t < C){ psb[t]=sm1; pqb[t]=sq1; }
  }
}

// ---------------- resumable chunked signature scan (compact fallback path) ----------------
template<int C, int NS, int CH>
__global__ __launch_bounds__(256) void sig_chunk(
    const float* __restrict__ path,
    float* __restrict__ chk,
    float* __restrict__ st3, float* __restrict__ st2,
    float* __restrict__ st1, float* __restrict__ stx,
    int lc)
{
  constexpr int C2 = C*C, C3 = C*C*C, S = C + C2 + C3;
  constexpr int SLICE = (C3 + NS - 1)/NS;
  constexpr int EPT = (SLICE + 255)/256;
  constexpr int QPT = (C2 + 255)/256;
  int b = blockIdx.x / NS, sl = blockIdx.x - b*NS;
  int t = threadIdx.x;
  __shared__ float ds[C]; __shared__ float s1s[C];
  __shared__ float s2s[C2]; __shared__ float Qs[C2];
  __shared__ float xprev[C];
  float v[EPT];
  int qidx[EPT], kidx[EPT]; bool ok[EPT];
  const int lin0 = sl*SLICE;
  const int lend = min(lin0 + SLICE, C3);
  #pragma unroll
  for (int e=0;e<EPT;++e){
    int lin = lin0 + e*256 + t;
    ok[e] = lin < lend;
    int q = (lin < C3) ? lin / C : 0;
    qidx[e] = q; kidx[e] = (lin < C3) ? (lin - q*C) : 0;
  }
  if (lc == 0){
    #pragma unroll
    for (int e=0;e<EPT;++e) v[e] = 0.f;
    for (int i=t;i<C2;i+=256) s2s[i] = 0.f;
    if (t < C){ s1s[t]=0.f; xprev[t]=0.f; }
  } else {
    #pragma unroll
    for (int e=0;e<EPT;++e) v[e] = ok[e] ? st3[(size_t)b*C3 + lin0 + e*256 + t] : 0.f;
    for (int i=t;i<C2;i+=256) s2s[i] = st2[(size_t)b*C2 + i];
    if (t < C){ s1s[t] = st1[b*C + t]; xprev[t] = stx[b*C + t]; }
  }
  const float* prow = path + (size_t)b*L_*C;
  const bool wr = (sl == 0);
  for (int il=0; il<CH; ++il){
    int l = lc*CH + il;
    __syncthreads();
    if (t < C){ float xv = prow[l*C + t]; ds[t] = xv - xprev[t]; xprev[t] = xv; }
    __syncthreads();
    float* crow = chk + ((size_t)(b*CH + il))*S;
    #pragma unroll
    for (int qq=0;qq<QPT;++qq){
      int q = t + qq*256;
      if (q < C2){
        int i = q / C; int j = q - i*C;
        float di = ds[i], dj = ds[j], s1i = s1s[i], s2v = s2s[q];
        Qs[q] = fmaf(dj, fmaf(di, (1.f/6.f), 0.5f*s1i), s2v);
        float n2 = fmaf(dj, fmaf(di, 0.5f, s1i), s2v);
        s2s[q] = n2;
        if (wr) crow[C+q] = n2;
      }
    }
    __syncthreads();
    #pragma unroll
    for (int e=0;e<EPT;++e){
      if (ok[e]){
        float nv = fmaf(Qs[qidx[e]], ds[kidx[e]], v[e]);
        v[e] = nv;
        crow[C + C2 + lin0 + e*256 + t] = nv;
      }
    }
    if (t < C){
      float n1 = s1s[t] + ds[t];
      s1s[t] = n1;
      if (wr) crow[t] = n1;
    }
  }
  #pragma unroll
  for (int e=0;e<EPT;++e) if (ok[e]) st3[(size_t)b*C3 + lin0 + e*256 + t] = v[e];
  if (wr){
    __syncthreads();
    for (int i=t;i<C2;i+=256) st2[(size_t)b*C2 + i] = s2s[i];
    if (t < C){ st1[b*C + t] = s1s[t]; stx[b*C + t] = xprev[t]; }
  }
}

// ---------------- batchnorm stats (zero-pads mu/inv to KP) ----------------
__global__ __launch_bounds__(256) void bn_stats(
    const float* __restrict__ psum, const float* __restrict__ psq,
    float* __restrict__ mu, float* __restrict__ inv, int S, int KP, float invN)
{
  int c = blockIdx.x*256 + threadIdx.x;
  if (c >= KP) return;
  if (c >= S){ mu[c] = 0.f; inv[c] = 0.f; return; }
  float s = 0.f, q = 0.f;
  for (int b=0;b<B_;++b){ s += psum[(size_t)b*S + c]; q += psq[(size_t)b*S + c]; }
  float m = s * invN;
  float var = fmaxf(fmaf(q, invN, -m*m), 0.f);
  mu[c] = m;
  inv[c] = 1.f / sqrtf(var + 1e-5f);
}

// ---------------- W-prep: pack 256*W (NO inv — A is normalized in gemm!) ----------------
__global__ __launch_bounds__(256) void wprep_k(
    const void* __restrict__ W,
    _Float16* __restrict__ whi, _Float16* __restrict__ wlo,
    int K, int nT, const int* __restrict__ flag)
{
  const int isbf = *flag;
  int idx = blockIdx.x*256 + threadIdx.x;
  if (idx >= nT*320) return;
  int kt = idx / 320; int rem = idx - kt*320;
  int j = rem >> 2, cg = (rem & 3) << 3;
  unsigned uh[4], ul[4];
  #pragma unroll
  for (int e=0;e<8;e+=2){
    int c0 = kt*32 + cg + e, c1 = c0 + 1;
    float w0 = (c0 < K) ? 256.f*ldw(W, (size_t)j*K + c0, isbf) : 0.f;
    float w1 = (c1 < K) ? 256.f*ldw(W, (size_t)j*K + c1, isbf) : 0.f;
    _Float16 h0 = (_Float16)w0, h1 = (_Float16)w1;
    _Float16 l0 = (_Float16)(w0 - (float)h0), l1 = (_Float16)(w1 - (float)h1);
    uh[e>>1] = pack2(h0, h1); ul[e>>1] = pack2(l0, l1);
  }
  uint4 vh; vh.x=uh[0]; vh.y=uh[1]; vh.z=uh[2]; vh.w=uh[3];
  uint4 vl; vl.x=ul[0]; vl.y=ul[1]; vl.z=ul[2]; vl.w=ul[3];
  size_t base = ((size_t)kt*80 + j)*32 + cg;
  *(uint4*)&whi[base] = vh;
  *(uint4*)&wlo[base] = vl;
}

// ---------------- MFMA GEMM v2: normalized A (fp16 hi/lo), packed 256*W B ----------------
__global__ __launch_bounds__(256) void gemm_mfma(
    const float* __restrict__ X, const float* __restrict__ mu, const float* __restrict__ inv,
    const _Float16* __restrict__ whi, const _Float16* __restrict__ wlo,
    float* __restrict__ part, int SP, int nT, int tpc)
{
  __shared__ _Float16 Ah[64][AP];
  __shared__ _Float16 Al[64][AP];
  __shared__ _Float16 Bh[80][AP];
  __shared__ _Float16 Bl[80][AP];
  int t = threadIdx.x;
  int mb = blockIdx.x, ks = blockIdx.y;
  int m0 = mb*64;
  int kt0 = ks*tpc, kt1 = min(kt0 + tpc, nT);
  int lane = t & 63, w = t >> 6;
  int ln = lane & 15, quad = lane >> 4;
  int q8 = quad*8;
  int ar = t >> 2, acg = (t & 3) << 3;
  const float* arow_p = X + (size_t)(m0 + ar)*SP + acg;

  floatx4 acc[5];
  #pragma unroll
  for (int nt=0; nt<5; ++nt) acc[nt] = (floatx4){0.f,0.f,0.f,0.f};

  float4 pf0, pf1, pm0, pm1, pv0, pv1;
  if (kt0 < kt1){
    int kb = kt0 << 5;
    pf0 = *(const float4*)(arow_p + kb);
    pf1 = *(const float4*)(arow_p + kb + 4);
    pm0 = *(const float4*)(mu + kb + acg);
    pm1 = *(const float4*)(mu + kb + acg + 4);
    pv0 = *(const float4*)(inv + kb + acg);
    pv1 = *(const float4*)(inv + kb + acg + 4);
  }

  for (int kt=kt0; kt<kt1; ++kt){
    __syncthreads();
    {
      float xv[8], mv[8], iv[8];
      *(float4*)&xv[0] = pf0; *(float4*)&xv[4] = pf1;
      *(float4*)&mv[0] = pm0; *(float4*)&mv[4] = pm1;
      *(float4*)&iv[0] = pv0; *(float4*)&iv[4] = pv1;
      unsigned uh[4], ul[4];
      #pragma unroll
      for (int e=0; e<8; e+=2){
        float n0 = (xv[e]   - mv[e])   * iv[e];
        float n1 = (xv[e+1] - mv[e+1]) * iv[e+1];
        _Float16 h0 = (_Float16)n0, h1 = (_Float16)n1;
        _Float16 l0 = (_Float16)(n0 - (float)h0), l1 = (_Float16)(n1 - (float)h1);
        uh[e>>1] = pack2(h0, h1); ul[e>>1] = pack2(l0, l1);
      }
      uint4 vh; vh.x=uh[0]; vh.y=uh[1]; vh.z=uh[2]; vh.w=uh[3];
      uint4 vl; vl.x=ul[0]; vl.y=ul[1]; vl.z=ul[2]; vl.w=ul[3];
      *(uint4*)&Ah[ar][acg] = vh;
      *(uint4*)&Al[ar][acg] = vl;
    }
    {
      const _Float16* bh = whi + (size_t)kt*80*32;
      const _Float16* bl = wlo + (size_t)kt*80*32;
      #pragma unroll
      for (int it=0; it<2; ++it){
        int idx = it*256 + t;
        if (idx < 320){
          int j = idx >> 2, cg = (idx & 3) << 3;
          *(uint4*)&Bh[j][cg] = *(const uint4*)(bh + j*32 + cg);
          *(uint4*)&Bl[j][cg] = *(const uint4*)(bl + j*32 + cg);
        }
      }
    }
    __syncthreads();
    if (kt+1 < kt1){
      int kb = (kt+1) << 5;
      pf0 = *(const float4*)(arow_p + kb);
      pf1 = *(const float4*)(arow_p + kb + 4);
      pm0 = *(const float4*)(mu + kb + acg);
      pm1 = *(const float4*)(mu + kb + acg + 4);
      pv0 = *(const float4*)(inv + kb + acg);
      pv1 = *(const float4*)(inv + kb + acg + 4);
    }
    half8 ah = *(const half8*)&Ah[w*16 + ln][q8];
    half8 al = *(const half8*)&Al[w*16 + ln][q8];
    half8 bh[5], bl[5];
    #pragma unroll
    for (int nt=0; nt<5; ++nt){
      bh[nt] = *(const half8*)&Bh[nt*16 + ln][q8];
      bl[nt] = *(const half8*)&Bl[nt*16 + ln][q8];
    }
    #pragma unroll
    for (int nt=0; nt<5; ++nt){
      acc[nt] = __builtin_amdgcn_mfma_f32_16x16x32_f16(ah, bh[nt], acc[nt], 0, 0, 0);
      acc[nt] = __builtin_amdgcn_mfma_f32_16x16x32_f16(al, bh[nt], acc[nt], 0, 0, 0);
      acc[nt] = __builtin_amdgcn_mfma_f32_16x16x32_f16(ah, bl[nt], acc[nt], 0, 0, 0);
    }
  }
  float* pb = part + (size_t)ks*2048*80;
  #pragma unroll
  for (int nt=0; nt<5; ++nt)
    #pragma unroll
    for (int r=0; r<4; ++r){
      int m = m0 + w*16 + quad*4 + r;
      int n = nt*16 + ln;
      pb[(size_t)m*80 + n] = acc[nt][r];
    }
}

// ---------------- fp32 fallback GEMM (compact path) ----------------
__global__ __launch_bounds__(256) void gemm_bn(
    const float* __restrict__ X, const float* __restrict__ mu, const float* __restrict__ inv,
    const void* __restrict__ W,
    float* __restrict__ part, int K, int tpc, const int* __restrict__ flag, int prows)
{
  const int isbf = *flag;
  int mb = blockIdx.x, ks = blockIdx.y;
  int nT = (K + 31) >> 5;
  int kt0 = ks*tpc, kt1 = min(kt0 + tpc, nT);
  __shared__ __align__(16) float xs[32][132];
  __shared__ float wsm[32][84];
  int t = threadIdx.x;
  int tm = t & 15, tj = t >> 4;
  int m0 = mb*128;
  float acc[8][5];
  #pragma unroll
  for (int i=0;i<8;++i)
    #pragma unroll
    for (int j5=0;j5<5;++j5) acc[i][j5] = 0.f;
  int cx = t & 31, rx = t >> 5;
  for (int kt=kt0; kt<kt1; ++kt){
    int kb = kt << 5;
    __syncthreads();
    int c = kb + cx;
    bool cv = c < K;
    float m  = cv ? mu[c]  : 0.f;
    float iv = cv ? inv[c] : 0.f;
    #pragma unroll
    for (int i=0;i<16;++i){
      int row = i*8 + rx;
      float xv = cv ? X[(size_t)(m0+row)*K + c] : 0.f;
      xs[cx][row] = (xv - m) * iv;
    }
    #pragma unroll
    for (int i=0;i<10;++i){
      int row = i*8 + rx;
      wsm[cx][row] = cv ? ldw(W, (size_t)row*K + c, isbf) : 0.f;
    }
    __syncthreads();
    #pragma unroll 2
    for (int kk=0;kk<32;++kk){
      float xv[8]; float wv[5];
      *(float4*)&xv[0] = *(const float4*)&xs[kk][tm*8];
      *(float4*)&xv[4] = *(const float4*)&xs[kk][tm*8+4];
      #pragma unroll
      for (int j5=0;j5<5;++j5) wv[j5] = wsm[kk][tj + j5*16];
      #pragma unroll
      for (int i=0;i<8;++i)
        #pragma unroll
        for (int j5=0;j5<5;++j5)
          acc[i][j5] = fmaf(xv[i], wv[j5], acc[i][j5]);
    }
  }
  float* pb = part + (size_t)ks*prows*80;
  #pragma unroll
  for (int i=0;i<8;++i){
    int m = m0 + tm*8 + i;
    #pragma unroll
    for (int j5=0;j5<5;++j5)
      pb[(size_t)m*80 + tj + j5*16] = acc[i][j5];
  }
}

// ---------------- reduce partials + layer0 biases (big path; scale 1/256) ----------------
__global__ __launch_bounds__(256) void greduce(
    const float* __restrict__ part,
    const void* __restrict__ bih, const void* __restrict__ bhh,
    float* __restrict__ G, int KS, const int* __restrict__ flag, float scale)
{
  const int isbf = *flag;
  int idx = blockIdx.x*256 + threadIdx.x;
  if (idx >= 2048*80) return;
  int j = idx % 80;
  float s = 0.f;
  for (int k=0;k<KS;++k) s += part[(size_t)k*2048*80 + idx];
  G[idx] = fmaf(s, scale, ldw(bih, j, isbf) + ldw(bhh, j, isbf));
}

// ---------------- reduce chunk partials (compact path) ----------------
template<int CH>
__global__ __launch_bounds__(256) void greduce_chunk(
    const float* __restrict__ part,
    const void* __restrict__ bih, const void* __restrict__ bhh,
    float* __restrict__ G, int KS, const int* __restrict__ flag, int lc)
{
  const int isbf = *flag;
  int idx = blockIdx.x*256 + threadIdx.x;
  if (idx >= B_*CH*80) return;
  int j = idx % 80;
  int rc = idx / 80;
  int b = rc / CH, il = rc % CH;
  float s = ldw(bih, j, isbf) + ldw(bhh, j, isbf);
  for (int k=0;k<KS;++k) s += part[(size_t)k*B_*CH*80 + idx];
  G[((size_t)b*L_ + lc*CH + il)*80 + j] = s;
}

// ---------------- pipelined single-wave 2-layer LSTM, readlane broadcasts ----------------
// 1 wave/batch. Half A (lanes 0-31): layer0 step i; half B (lanes 32-63):
// layer1 step i-1 (skewed pipeline, both depend only on h0(i-1),h1(i-2)).
// ZERO DS ops in the loop: h broadcast via v_readlane at constant lanes
// (h0 from lanes 0-19, h1 from lanes 32-51) — SALU-latency, not ~100-cyc
// ds_bpermute like __shfl with lane-varying index.
__global__ __launch_bounds__(64) void lstm2_pipe(
    const float* __restrict__ G0,
    const void* __restrict__ whh0,
    const void* __restrict__ wih1,
    const void* __restrict__ whh1,
    const void* __restrict__ bih1,
    const void* __restrict__ bhh1,
    float* __restrict__ oseq,
    float* __restrict__ dout,
    const void* __restrict__ linw,
    const void* __restrict__ linb,
    const int* __restrict__ flag)
{
  const int isbf = *flag;
  int b = blockIdx.x; int t = threadIdx.x;
  int half = t >> 5, k0 = t & 31;
  int k = (k0 < 20) ? k0 : 19;          // clamp idle lanes (never read back)
  __shared__ float wsh[3*1600];
  if (isbf){
    const __hip_bfloat16* s0 = (const __hip_bfloat16*)whh0;
    const __hip_bfloat16* s1 = (const __hip_bfloat16*)wih1;
    const __hip_bfloat16* s2 = (const __hip_bfloat16*)whh1;
    for (int i=t;i<1600;i+=64){
      wsh[i] = bf2f(s0[i]); wsh[1600+i] = bf2f(s1[i]); wsh[3200+i] = bf2f(s2[i]);
    }
  } else {
    const float* s0 = (const float*)whh0;
    const float* s1 = (const float*)wih1;
    const float* s2 = (const float*)whh1;
    for (int i=t;i<1600;i+=64){
      wsh[i] = s0[i]; wsh[1600+i] = s1[i]; wsh[3200+i] = s2[i];
    }
  }
  __syncthreads();                       // once, before the scan
  // per-half weight selection: A: wA=Whh0, wB=0 ; B: wA=W1i, wB=W1h
  float wA[4][20], wB[4][20];
  int offA = half ? 1600 : 0;
  #pragma unroll
  for (int q=0;q<4;++q)
    #pragma unroll
    for (int j=0;j<20;++j){
      int row = q*20 + k;
      wA[q][j] = wsh[offA + row*20 + j];
      wB[q][j] = half ? wsh[3200 + row*20 + j] : 0.f;
    }
  float bias1[4];
  #pragma unroll
  for (int q=0;q<4;++q)
    bias1[q] = half ? (ldw(bih1, q*20+k, isbf) + ldw(bhh1, q*20+k, isbf)) : 0.f;
  float lw20[20]; float lb = 0.f;
  const bool fin = (dout != nullptr);
  if (fin){
    #pragma unroll
    for (int j=0;j<20;++j) lw20[j] = ldw(linw, j, isbf);
    lb = ldw(linb, 0, isbf);
  }
  float h0r[20], h1r[20];
  #pragma unroll
  for (int j=0;j<20;++j){ h0r[j]=0.f; h1r[j]=0.f; }
  float c = 0.f;                         // A lanes: c0 ; B lanes: c1
  const float* Gb = G0 + (size_t)b*L_*G4;
  float gc[4], gn[4];
  #pragma unroll
  for (int q=0;q<4;++q) gc[q] = Gb[q*20 + k];
  for (int i=0; i<=L_; ++i){
    int nx = (i+1 < L_) ? (i+1) : (L_-1);
    #pragma unroll
    for (int q=0;q<4;++q) gn[q] = Gb[nx*G4 + q*20 + k];
    // ---- unified gate dots (A: layer0 step i ; B: layer1 step i-1) ----
    float s[4];
    #pragma unroll
    for (int q=0;q<4;++q){
      float v = half ? bias1[q] : gc[q];
      #pragma unroll
      for (int j=0;j<20;++j) v = fmaf(wA[q][j], h0r[j], v);
      #pragma unroll
      for (int j=0;j<20;++j) v = fmaf(wB[q][j], h1r[j], v);
      s[q] = v;
    }
    float ig = sigf(s[0]), fg = sigf(s[1]);
    float gg = tanhf_fast(s[2]), og = sigf(s[3]);
    bool valid = half ? (i > 0) : (i < L_);
    float cn = fmaf(fg, c, ig*gg);
    float hn = og * tanhf_fast(cn);
    c  = valid ? cn : c;
    hn = valid ? hn : 0.f;
    if (oseq && half==1 && k0 < 20 && i >= 1)
      oseq[((size_t)b*L_ + (i-1))*20 + k] = hn;
    // ---- broadcast via readlane: h0 from lanes 0-19, h1 from lanes 32-51 ----
    #pragma unroll
    for (int j=0;j<20;++j) h0r[j] = rdlane(hn, j);
    #pragma unroll
    for (int j=0;j<20;++j) h1r[j] = rdlane(hn, 32+j);
    if (fin && i >= 1){
      float p = lb;
      #pragma unroll
      for (int j=0;j<20;++j){
        float h = h1r[j];
        float wv = (h >= 0.f) ? h : 0.01f*h;   // LeakyReLU(0.01)
        p = fmaf(lw20[j], wv, p);
      }
      if (t == 0) dout[b*L_ + (i-1)] = p;
    }
    #pragma unroll
    for (int q=0;q<4;++q) gc[q] = gn[q];
  }
}

extern "C" void kernel_launch(void* const* d_in, const int* in_sizes, int n_in,
                              void* d_out, int out_size, void* d_ws, size_t ws_size,
                              hipStream_t stream)
{
  (void)out_size;
  auto P = [&](int i){ return (const void*)d_in[i]; };
  float* dout = (float*)d_out;

  static const int EXP[31] = {40960,1280,64,512,8,
    2020720,1600,80,80,1600,1600,80,80,
    673600,1600,80,80,1600,1600,80,80,
    673600,1600,80,80,1600,1600,80,80,
    20,1};
  int bad = (n_in == 31) ? -1 : 99;
  if (bad < 0) for (int i=0;i<31;++i) if (in_sizes[i] != EXP[i]){ bad = i; break; }
  if (bad >= 0){
    fill_k<<<dim3(8), dim3(256), 0, stream>>>(dout, 1000.f + (float)bad);
    return;
  }

  constexpr int CH = 16, NCH = L_/CH;
  const int S1 = 25259, S2 = 8420;
  const int nT1 = (S1+31)/32, nT2 = (S2+31)/32;   // 790, 264
  const int KP1 = nT1*32, KP2 = nT2*32;           // 25280, 8448
  const int SP1 = 25280, SP2 = 8420;

  float* ws = (float*)d_ws;
  size_t off = 0;
  auto alloc = [&](size_t n){ float* p = ws + off; off += (n+3)&~(size_t)3; return p; };
  float* a    = alloc(2048*29);
  float* o1   = alloc(2048*20);
  float* o2   = alloc(2048*20);
  float* mu   = alloc(KP1);
  float* inv  = alloc(KP1);
  float* psum = alloc((size_t)B_*S1);
  float* psq  = alloc((size_t)B_*S1);
  float* G    = alloc(2048*80);
  int*   flag = (int*)alloc(64);

  const bool big     = ws_size >= (size_t)234*1000*1000;
  const bool compact = ws_size >= (size_t)58*1000*1000;
  if (!big && !compact){
    float mb = (float)(ws_size / (1024.0*1024.0));
    fill_k<<<dim3(8), dim3(256), 0, stream>>>(dout, 4000.f + mb);
    return;
  }

  detect_k<<<dim3(1), dim3(256), 0, stream>>>(P(1), 1280, flag);
  augment_k<<<dim3(2048), dim3(64), 0, stream>>>(P(0), P(1), P(2), P(3), P(4), a, flag);

  if (big){
    const int KS = 16;
    float* part = alloc((size_t)KS*2048*80);
    float* whif = alloc((size_t)nT1*1280);
    float* wlof = alloc((size_t)nT1*1280);
    float* sigb = alloc((size_t)2048*SP1);
    _Float16* whi = (_Float16*)whif;
    _Float16* wlo = (_Float16*)wlof;
    const int tpc1 = (nT1 + KS-1)/KS;
    const int tpc2 = (nT2 + KS-1)/KS;
    const float sc = 1.f/256.f;

    auto big_stage = [&](const float* x, int S, int KP, int SP, int nT, int tpc,
                         int wih0_i, int bih0_i, int bhh0_i, int whh0_i,
                         int wih1_i, int whh1_i, int bih1_i, int bhh1_i,
                         float* oseq, float* dd, int lw_i, int lb_i, bool c29)
    {
      if (c29) sig_scan<29,64,true><<<dim3(B_*64), dim3(256), 0, stream>>>(x, sigb, psum, psq, SP);
      else     sig_scan<20,32,true><<<dim3(B_*32), dim3(256), 0, stream>>>(x, sigb, psum, psq, SP);
      bn_stats<<<dim3((KP+255)/256), dim3(256), 0, stream>>>(psum, psq, mu, inv, S, KP, 1.f/2048.f);
      wprep_k<<<dim3((nT*320+255)/256), dim3(256), 0, stream>>>(P(wih0_i), whi, wlo, S, nT, flag);
      gemm_mfma<<<dim3(32, KS), dim3(256), 0, stream>>>(sigb, mu, inv, whi, wlo, part, SP, nT, tpc);
      greduce<<<dim3(640), dim3(256), 0, stream>>>(part, P(bih0_i), P(bhh0_i), G, KS, flag, sc);
      lstm2_pipe<<<dim3(B_), dim3(64), 0, stream>>>(G, P(whh0_i), P(wih1_i), P(whh1_i), P(bih1_i), P(bhh1_i),
                                                    oseq, dd,
                                                    lw_i >= 0 ? P(lw_i) : nullptr,
                                                    lb_i >= 0 ? P(lb_i) : nullptr, flag);
    };

    big_stage(a,  S1, KP1, SP1, nT1, tpc1,  5, 7, 8, 6,  9,10,11,12, o1, nullptr, -1, -1, true);
    big_stage(o1, S2, KP2, SP2, nT2, tpc2, 13,15,16,14, 17,18,19,20, o2, nullptr, -1, -1, false);
    big_stage(o2, S2, KP2, SP2, nT2, tpc2, 21,23,24,22, 25,26,27,28, nullptr, dout, 29, 30, false);
  } else {
    float* st3  = alloc((size_t)B_*29*29*29);
    float* st2  = alloc((size_t)B_*29*29);
    float* st1  = alloc((size_t)B_*29);
    float* stx  = alloc((size_t)B_*29);
    const int KSC = 128;
    float* part = alloc((size_t)KSC*B_*CH*80);
    float* chk  = alloc((size_t)B_*CH*S1);
    const int tpc1 = (nT1 + KSC-1)/KSC;
    const int tpc2 = (nT2 + KSC-1)/KSC;
    const int GRED = (B_*CH*80 + 255)/256;

    sig_scan<29,64,false><<<dim3(B_*64), dim3(256), 0, stream>>>(a, nullptr, psum, psq, S1);
    bn_stats<<<dim3((KP1+255)/256), dim3(256), 0, stream>>>(psum, psq, mu, inv, S1, KP1, 1.f/2048.f);
    for (int lc=0; lc<NCH; ++lc){
      sig_chunk<29,16,CH><<<dim3(B_*16), dim3(256), 0, stream>>>(a, chk, st3, st2, st1, stx, lc);
      gemm_bn<<<dim3(2, KSC), dim3(256), 0, stream>>>(chk, mu, inv, P(5), part, S1, tpc1, flag, B_*CH);
      greduce_chunk<CH><<<dim3(GRED), dim3(256), 0, stream>>>(part, P(7), P(8), G, KSC, flag, lc);
    }
    lstm2_pipe<<<dim3(B_), dim3(64), 0, stream>>>(G, P(6), P(9), P(10), P(11), P(12),
                                                  o1, nullptr, nullptr, nullptr, flag);

    sig_scan<20,32,false><<<dim3(B_*32), dim3(256), 0, stream>>>(o1, nullptr, psum, psq, S2);
    bn_stats<<<dim3((KP2+255)/256), dim3(256), 0, stream>>>(psum, psq, mu, inv, S2, KP2, 1.f/2048.f);
    for (int lc=0; lc<NCH; ++lc){
      sig_chunk<20,8,CH><<<dim3(B_*8), dim3(256), 0, stream>>>(o1, chk, st3, st2, st1, stx, lc);
      gemm_bn<<<dim3(2, KSC), dim3(256), 0, stream>>>(chk, mu, inv, P(13), part, S2, tpc2, flag, B_*CH);
      greduce_chunk<CH><<<dim3(GRED), dim3(256), 0, stream>>>(part, P(15), P(16), G, KSC, flag, lc);
    }
    lstm2_pipe<<<dim3(B_), dim3(64), 0, stream>>>(G, P(14), P(17), P(18), P(19), P(20),
                                                  o2, nullptr, nullptr, nullptr, flag);

    sig_scan<20,32,false><<<dim3(B_*32), dim3(256), 0, stream>>>(o2, nullptr, psum, psq, S2);
    bn_stats<<<dim3((KP2+255)/256), dim3(256), 0, stream>>>(psum, psq, mu, inv, S2, KP2, 1.f/2048.f);
    for (int lc=0; lc<NCH; ++lc){
      sig_chunk<20,8,CH><<<dim3(B_*8), dim3(256), 0, stream>>>(o2, chk, st3, st2, st1, stx, lc);
      gemm_bn<<<dim3(2, KSC), dim3(256), 0, stream>>>(chk, mu, inv, P(21), part, S2, tpc2, flag, B_*CH);
      greduce_chunk<CH><<<dim3(GRED), dim3(256), 0, stream>>>(part, P(23), P(24), G, KSC, flag, lc);
    }
    lstm2_pipe<<<dim3(B_), dim3(64), 0, stream>>>(G, P(22), P(25), P(26), P(27), P(28),
                                                  nullptr, dout, P(29), P(30), flag);
  }
}

// Round 15
// 806.135 us; speedup vs baseline: 1.0921x; 1.0043x over previous
//
#include <hip/hip_runtime.h>
#include <hip/hip_bf16.h>

#define B_ 16
#define L_ 128
#define G4 80   // 4*H gates
#define AP 40   // padded LDS half-stride

typedef _Float16 half8 __attribute__((ext_vector_type(8)));
typedef float floatx4 __attribute__((ext_vector_type(4)));

__device__ __forceinline__ float bf2f(const __hip_bfloat16 x){ return __bfloat162float(x); }

// dtype-flexible load: isbf=1 -> bf16, isbf=0 -> fp32  (OUT of hot loops only!)
__device__ __forceinline__ float ldw(const void* p, size_t i, int isbf){
  return isbf ? __bfloat162float(((const __hip_bfloat16*)p)[i])
              : ((const float*)p)[i];
}

__device__ __forceinline__ unsigned pack2(_Float16 a, _Float16 b){
  union{ _Float16 h[2]; unsigned u; } z; z.h[0]=a; z.h[1]=b; return z.u;
}

// fast sigmoid/tanh (v_exp + v_rcp; ~1e-6 rel err, inside accuracy budget)
__device__ __forceinline__ float sigf(float x){
  return __builtin_amdgcn_rcpf(1.f + __expf(-x));
}
__device__ __forceinline__ float tanhf_fast(float x){
  float e = __expf(2.f*x);
  return (e - 1.f) * __builtin_amdgcn_rcpf(e + 1.f);
}
// broadcast lane j's value wave-wide via v_readlane (no DS op!)
__device__ __forceinline__ float rdlane(float v, int lane){
  return __int_as_float(__builtin_amdgcn_readlane(__float_as_int(v), lane));
}

// ---------------- diagnostic fill ----------------
__global__ __launch_bounds__(256) void fill_k(float* out, float v){
  int i = blockIdx.x*256 + threadIdx.x;
  if (i < 2048) out[i] = v;
}

// ---------------- input dtype detection ----------------
__global__ __launch_bounds__(256) void detect_k(const void* w, int n, int* flag){
  int t = threadIdx.x;
  const __hip_bfloat16* hb = (const __hip_bfloat16*)w;
  int bad = 0;
  for (int i=t; i<n; i+=256){
    float v = fabsf(bf2f(hb[i]));
    if (!(v < 16.f) || (v != 0.f && v < 1e-5f)) bad++;
  }
  __shared__ int s[256];
  s[t] = bad; __syncthreads();
  for (int k=128;k>0;k>>=1){ if (t<k) s[t]+=s[t+k]; __syncthreads(); }
  if (t==0) *flag = (s[0]*4 > n) ? 0 : 1;
}

// ---------------- augment ----------------
__global__ __launch_bounds__(64) void augment_k(
    const void* __restrict__ inp,
    const void* __restrict__ w1, const void* __restrict__ b1,
    const void* __restrict__ w2, const void* __restrict__ b2,
    float* __restrict__ a, const int* __restrict__ flag)
{
  const int isbf = *flag;
  int pos = blockIdx.x; int t = threadIdx.x;
  __shared__ float xin[20]; __shared__ float hsh[64];
  if (t < 20) xin[t] = ldw(inp, pos*20 + t, isbf);
  __syncthreads();
  float acc = ldw(b1, t, isbf);
  #pragma unroll
  for (int k=0;k<20;++k) acc = fmaf(ldw(w1, t*20+k, isbf), xin[k], acc);
  hsh[t] = fmaxf(acc, 0.f);
  __syncthreads();
  float* arow = a + pos*29;
  if (t < 8){
    float s = ldw(b2, t, isbf);
    #pragma unroll
    for (int k=0;k<64;++k) s = fmaf(ldw(w2, t*64+k, isbf), hsh[k], s);
    arow[21+t] = s;
  }
  if (t == 0) arow[0] = (float)((pos & (L_-1)) * (1.0/127.0));
  if (t < 20) arow[1+t] = xin[t];
}

// ---------------- streamed depth-3 signature (stats + optional materialize, padded stride) ----------------
template<int C, int NS, bool WRITE_SIG>
__global__ __launch_bounds__(256) void sig_scan(
    const float* __restrict__ path,
    float* __restrict__ sig,
    float* __restrict__ psum, float* __restrict__ psq, int SP)
{
  constexpr int C2 = C*C, C3 = C*C*C, S = C + C2 + C3;
  constexpr int SLICE = (C3 + NS - 1)/NS;
  constexpr int EPT = (SLICE + 255)/256;
  constexpr int QPT = (C2 + 255)/256;
  int b = blockIdx.x / NS, sl = blockIdx.x - b*NS;
  int t = threadIdx.x;
  __shared__ float ds[C]; __shared__ float s1s[C];
  __shared__ float s2s[C2]; __shared__ float Qs[C2];
  __shared__ float xprev[C];
  float v[EPT], vs[EPT], vq[EPT];
  int qidx[EPT], kidx[EPT]; bool ok[EPT];
  const int lin0 = sl*SLICE;
  const int lend = min(lin0 + SLICE, C3);
  #pragma unroll
  for (int e=0;e<EPT;++e){
    int lin = lin0 + e*256 + t;
    ok[e] = lin < lend;
    int q = (lin < C3) ? lin / C : 0;
    qidx[e] = q; kidx[e] = (lin < C3) ? (lin - q*C) : 0;
    v[e]=0.f; vs[e]=0.f; vq[e]=0.f;
  }
  float sm1=0.f, sq1=0.f;
  float sm2[QPT], sq2[QPT];
  #pragma unroll
  for (int qq=0;qq<QPT;++qq){ sm2[qq]=0.f; sq2[qq]=0.f; }
  for (int i=t;i<C2;i+=256) s2s[i]=0.f;
  if (t < C){ s1s[t]=0.f; xprev[t]=0.f; }
  const float* prow = path + (size_t)b*L_*C;
  float* srow0 = WRITE_SIG ? (sig + (size_t)b*L_*SP) : nullptr;
  const bool wr = (sl == 0);
  for (int l=0;l<L_;++l){
    __syncthreads();
    if (t < C){ float xv = prow[l*C + t]; ds[t] = xv - xprev[t]; xprev[t] = xv; }
    __syncthreads();
    float* srow = WRITE_SIG ? (srow0 + (size_t)l*SP) : nullptr;
    #pragma unroll
    for (int qq=0;qq<QPT;++qq){
      int q = t + qq*256;
      if (q < C2){
        int i = q / C; int j = q - i*C;
        float di = ds[i], dj = ds[j], s1i = s1s[i], s2v = s2s[q];
        Qs[q] = fmaf(dj, fmaf(di, (1.f/6.f), 0.5f*s1i), s2v);
        float n2 = fmaf(dj, fmaf(di, 0.5f, s1i), s2v);
        s2s[q] = n2;
        if (wr){
          if constexpr (WRITE_SIG) srow[C+q] = n2;
          sm2[qq] += n2; sq2[qq] = fmaf(n2, n2, sq2[qq]);
        }
      }
    }
    __syncthreads();
    #pragma unroll
    for (int e=0;e<EPT;++e){
      if (ok[e]){
        float nv = fmaf(Qs[qidx[e]], ds[kidx[e]], v[e]);
        v[e] = nv;
        if constexpr (WRITE_SIG) srow[C + C2 + lin0 + e*256 + t] = nv;
        vs[e] += nv; vq[e] = fmaf(nv, nv, vq[e]);
      }
    }
    if (t < C){
      float n1 = s1s[t] + ds[t];
      s1s[t] = n1;
      if (wr){
        if constexpr (WRITE_SIG) srow[t] = n1;
        sm1 += n1; sq1 = fmaf(n1, n1, sq1);
      }
    }
  }
  float* psb = psum + (size_t)b*S; float* pqb = psq + (size_t)b*S;
  #pragma unroll
  for (int e=0;e<EPT;++e){
    if (ok[e]){
      int c = C + C2 + lin0 + e*256 + t;
      psb[c] = vs[e]; pqb[c] = vq[e];
    }
  }
  if (wr){
    #pragma unroll
    for (int qq=0;qq<QPT;++qq){ int q = t + qq*256; if (q < C2){ psb[C+q]=sm2[qq]; pqb[C+q]=sq2[qq]; } }
    if (t < C){ psb[t]=sm1; pqb[t]=sq1; }
  }
}

// ---------------- resumable chunked signature scan (compact fallback path) ----------------
template<int C, int NS, int CH>
__global__ __launch_bounds__(256) void sig_chunk(
    const float* __restrict__ path,
    float* __restrict__ chk,
    float* __restrict__ st3, float* __restrict__ st2,
    float* __restrict__ st1, float* __restrict__ stx,
    int lc)
{
  constexpr int C2 = C*C, C3 = C*C*C, S = C + C2 + C3;
  constexpr int SLICE = (C3 + NS - 1)/NS;
  constexpr int EPT = (SLICE + 255)/256;
  constexpr int QPT = (C2 + 255)/256;
  int b = blockIdx.x / NS, sl = blockIdx.x - b*NS;
  int t = threadIdx.x;
  __shared__ float ds[C]; __shared__ float s1s[C];
  __shared__ float s2s[C2]; __shared__ float Qs[C2];
  __shared__ float xprev[C];
  float v[EPT];
  int qidx[EPT], kidx[EPT]; bool ok[EPT];
  const int lin0 = sl*SLICE;
  const int lend = min(lin0 + SLICE, C3);
  #pragma unroll
  for (int e=0;e<EPT;++e){
    int lin = lin0 + e*256 + t;
    ok[e] = lin < lend;
    int q = (lin < C3) ? lin / C : 0;
    qidx[e] = q; kidx[e] = (lin < C3) ? (lin - q*C) : 0;
  }
  if (lc == 0){
    #pragma unroll
    for (int e=0;e<EPT;++e) v[e] = 0.f;
    for (int i=t;i<C2;i+=256) s2s[i] = 0.f;
    if (t < C){ s1s[t]=0.f; xprev[t]=0.f; }
  } else {
    #pragma unroll
    for (int e=0;e<EPT;++e) v[e] = ok[e] ? st3[(size_t)b*C3 + lin0 + e*256 + t] : 0.f;
    for (int i=t;i<C2;i+=256) s2s[i] = st2[(size_t)b*C2 + i];
    if (t < C){ s1s[t] = st1[b*C + t]; xprev[t] = stx[b*C + t]; }
  }
  const float* prow = path + (size_t)b*L_*C;
  const bool wr = (sl == 0);
  for (int il=0; il<CH; ++il){
    int l = lc*CH + il;
    __syncthreads();
    if (t < C){ float xv = prow[l*C + t]; ds[t] = xv - xprev[t]; xprev[t] = xv; }
    __syncthreads();
    float* crow = chk + ((size_t)(b*CH + il))*S;
    #pragma unroll
    for (int qq=0;qq<QPT;++qq){
      int q = t + qq*256;
      if (q < C2){
        int i = q / C; int j = q - i*C;
        float di = ds[i], dj = ds[j], s1i = s1s[i], s2v = s2s[q];
        Qs[q] = fmaf(dj, fmaf(di, (1.f/6.f), 0.5f*s1i), s2v);
        float n2 = fmaf(dj, fmaf(di, 0.5f, s1i), s2v);
        s2s[q] = n2;
        if (wr) crow[C+q] = n2;
      }
    }
    __syncthreads();
    #pragma unroll
    for (int e=0;e<EPT;++e){
      if (ok[e]){
        float nv = fmaf(Qs[qidx[e]], ds[kidx[e]], v[e]);
        v[e] = nv;
        crow[C + C2 + lin0 + e*256 + t] = nv;
      }
    }
    if (t < C){
      float n1 = s1s[t] + ds[t];
      s1s[t] = n1;
      if (wr) crow[t] = n1;
    }
  }
  #pragma unroll
  for (int e=0;e<EPT;++e) if (ok[e]) st3[(size_t)b*C3 + lin0 + e*256 + t] = v[e];
  if (wr){
    __syncthreads();
    for (int i=t;i<C2;i+=256) st2[(size_t)b*C2 + i] = s2s[i];
    if (t < C){ st1[b*C + t] = s1s[t]; stx[b*C + t] = xprev[t]; }
  }
}

// ---------------- batchnorm stats (zero-pads mu/inv to KP) ----------------
__global__ __launch_bounds__(256) void bn_stats(
    const float* __restrict__ psum, const float* __restrict__ psq,
    float* __restrict__ mu, float* __restrict__ inv, int S, int KP, float invN)
{
  int c = blockIdx.x*256 + threadIdx.x;
  if (c >= KP) return;
  if (c >= S){ mu[c] = 0.f; inv[c] = 0.f; return; }
  float s = 0.f, q = 0.f;
  for (int b=0;b<B_;++b){ s += psum[(size_t)b*S + c]; q += psq[(size_t)b*S + c]; }
  float m = s * invN;
  float var = fmaxf(fmaf(q, invN, -m*m), 0.f);
  mu[c] = m;
  inv[c] = 1.f / sqrtf(var + 1e-5f);
}

// ---------------- W-prep: pack 256*W (NO inv — A is normalized in gemm!) ----------------
__global__ __launch_bounds__(256) void wprep_k(
    const void* __restrict__ W,
    _Float16* __restrict__ whi, _Float16* __restrict__ wlo,
    int K, int nT, const int* __restrict__ flag)
{
  const int isbf = *flag;
  int idx = blockIdx.x*256 + threadIdx.x;
  if (idx >= nT*320) return;
  int kt = idx / 320; int rem = idx - kt*320;
  int j = rem >> 2, cg = (rem & 3) << 3;
  unsigned uh[4], ul[4];
  #pragma unroll
  for (int e=0;e<8;e+=2){
    int c0 = kt*32 + cg + e, c1 = c0 + 1;
    float w0 = (c0 < K) ? 256.f*ldw(W, (size_t)j*K + c0, isbf) : 0.f;
    float w1 = (c1 < K) ? 256.f*ldw(W, (size_t)j*K + c1, isbf) : 0.f;
    _Float16 h0 = (_Float16)w0, h1 = (_Float16)w1;
    _Float16 l0 = (_Float16)(w0 - (float)h0), l1 = (_Float16)(w1 - (float)h1);
    uh[e>>1] = pack2(h0, h1); ul[e>>1] = pack2(l0, l1);
  }
  uint4 vh; vh.x=uh[0]; vh.y=uh[1]; vh.z=uh[2]; vh.w=uh[3];
  uint4 vl; vl.x=ul[0]; vl.y=ul[1]; vl.z=ul[2]; vl.w=ul[3];
  size_t base = ((size_t)kt*80 + j)*32 + cg;
  *(uint4*)&whi[base] = vh;
  *(uint4*)&wlo[base] = vl;
}

// ---------------- MFMA GEMM v2: normalized A (fp16 hi/lo), packed 256*W B ----------------
__global__ __launch_bounds__(256) void gemm_mfma(
    const float* __restrict__ X, const float* __restrict__ mu, const float* __restrict__ inv,
    const _Float16* __restrict__ whi, const _Float16* __restrict__ wlo,
    float* __restrict__ part, int SP, int nT, int tpc)
{
  __shared__ _Float16 Ah[64][AP];
  __shared__ _Float16 Al[64][AP];
  __shared__ _Float16 Bh[80][AP];
  __shared__ _Float16 Bl[80][AP];
  int t = threadIdx.x;
  int mb = blockIdx.x, ks = blockIdx.y;
  int m0 = mb*64;
  int kt0 = ks*tpc, kt1 = min(kt0 + tpc, nT);
  int lane = t & 63, w = t >> 6;
  int ln = lane & 15, quad = lane >> 4;
  int q8 = quad*8;
  int ar = t >> 2, acg = (t & 3) << 3;
  const float* arow_p = X + (size_t)(m0 + ar)*SP + acg;

  floatx4 acc[5];
  #pragma unroll
  for (int nt=0; nt<5; ++nt) acc[nt] = (floatx4){0.f,0.f,0.f,0.f};

  float4 pf0, pf1, pm0, pm1, pv0, pv1;
  if (kt0 < kt1){
    int kb = kt0 << 5;
    pf0 = *(const float4*)(arow_p + kb);
    pf1 = *(const float4*)(arow_p + kb + 4);
    pm0 = *(const float4*)(mu + kb + acg);
    pm1 = *(const float4*)(mu + kb + acg + 4);
    pv0 = *(const float4*)(inv + kb + acg);
    pv1 = *(const float4*)(inv + kb + acg + 4);
  }

  for (int kt=kt0; kt<kt1; ++kt){
    __syncthreads();
    {
      float xv[8], mv[8], iv[8];
      *(float4*)&xv[0] = pf0; *(float4*)&xv[4] = pf1;
      *(float4*)&mv[0] = pm0; *(float4*)&mv[4] = pm1;
      *(float4*)&iv[0] = pv0; *(float4*)&iv[4] = pv1;
      unsigned uh[4], ul[4];
      #pragma unroll
      for (int e=0; e<8; e+=2){
        float n0 = (xv[e]   - mv[e])   * iv[e];
        float n1 = (xv[e+1] - mv[e+1]) * iv[e+1];
        _Float16 h0 = (_Float16)n0, h1 = (_Float16)n1;
        _Float16 l0 = (_Float16)(n0 - (float)h0), l1 = (_Float16)(n1 - (float)h1);
        uh[e>>1] = pack2(h0, h1); ul[e>>1] = pack2(l0, l1);
      }
      uint4 vh; vh.x=uh[0]; vh.y=uh[1]; vh.z=uh[2]; vh.w=uh[3];
      uint4 vl; vl.x=ul[0]; vl.y=ul[1]; vl.z=ul[2]; vl.w=ul[3];
      *(uint4*)&Ah[ar][acg] = vh;
      *(uint4*)&Al[ar][acg] = vl;
    }
    {
      const _Float16* bh = whi + (size_t)kt*80*32;
      const _Float16* bl = wlo + (size_t)kt*80*32;
      #pragma unroll
      for (int it=0; it<2; ++it){
        int idx = it*256 + t;
        if (idx < 320){
          int j = idx >> 2, cg = (idx & 3) << 3;
          *(uint4*)&Bh[j][cg] = *(const uint4*)(bh + j*32 + cg);
          *(uint4*)&Bl[j][cg] = *(const uint4*)(bl + j*32 + cg);
        }
      }
    }
    __syncthreads();
    if (kt+1 < kt1){
      int kb = (kt+1) << 5;
      pf0 = *(const float4*)(arow_p + kb);
      pf1 = *(const float4*)(arow_p + kb + 4);
      pm0 = *(const float4*)(mu + kb + acg);
      pm1 = *(const float4*)(mu + kb + acg + 4);
      pv0 = *(const float4*)(inv + kb + acg);
      pv1 = *(const float4*)(inv + kb + acg + 4);
    }
    half8 ah = *(const half8*)&Ah[w*16 + ln][q8];
    half8 al = *(const half8*)&Al[w*16 + ln][q8];
    half8 bh[5], bl[5];
    #pragma unroll
    for (int nt=0; nt<5; ++nt){
      bh[nt] = *(const half8*)&Bh[nt*16 + ln][q8];
      bl[nt] = *(const half8*)&Bl[nt*16 + ln][q8];
    }
    #pragma unroll
    for (int nt=0; nt<5; ++nt){
      acc[nt] = __builtin_amdgcn_mfma_f32_16x16x32_f16(ah, bh[nt], acc[nt], 0, 0, 0);
      acc[nt] = __builtin_amdgcn_mfma_f32_16x16x32_f16(al, bh[nt], acc[nt], 0, 0, 0);
      acc[nt] = __builtin_amdgcn_mfma_f32_16x16x32_f16(ah, bl[nt], acc[nt], 0, 0, 0);
    }
  }
  float* pb = part + (size_t)ks*2048*80;
  #pragma unroll
  for (int nt=0; nt<5; ++nt)
    #pragma unroll
    for (int r=0; r<4; ++r){
      int m = m0 + w*16 + quad*4 + r;
      int n = nt*16 + ln;
      pb[(size_t)m*80 + n] = acc[nt][r];
    }
}

// ---------------- fp32 fallback GEMM (compact path) ----------------
__global__ __launch_bounds__(256) void gemm_bn(
    const float* __restrict__ X, const float* __restrict__ mu, const float* __restrict__ inv,
    const void* __restrict__ W,
    float* __restrict__ part, int K, int tpc, const int* __restrict__ flag, int prows)
{
  const int isbf = *flag;
  int mb = blockIdx.x, ks = blockIdx.y;
  int nT = (K + 31) >> 5;
  int kt0 = ks*tpc, kt1 = min(kt0 + tpc, nT);
  __shared__ __align__(16) float xs[32][132];
  __shared__ float wsm[32][84];
  int t = threadIdx.x;
  int tm = t & 15, tj = t >> 4;
  int m0 = mb*128;
  float acc[8][5];
  #pragma unroll
  for (int i=0;i<8;++i)
    #pragma unroll
    for (int j5=0;j5<5;++j5) acc[i][j5] = 0.f;
  int cx = t & 31, rx = t >> 5;
  for (int kt=kt0; kt<kt1; ++kt){
    int kb = kt << 5;
    __syncthreads();
    int c = kb + cx;
    bool cv = c < K;
    float m  = cv ? mu[c]  : 0.f;
    float iv = cv ? inv[c] : 0.f;
    #pragma unroll
    for (int i=0;i<16;++i){
      int row = i*8 + rx;
      float xv = cv ? X[(size_t)(m0+row)*K + c] : 0.f;
      xs[cx][row] = (xv - m) * iv;
    }
    #pragma unroll
    for (int i=0;i<10;++i){
      int row = i*8 + rx;
      wsm[cx][row] = cv ? ldw(W, (size_t)row*K + c, isbf) : 0.f;
    }
    __syncthreads();
    #pragma unroll 2
    for (int kk=0;kk<32;++kk){
      float xv[8]; float wv[5];
      *(float4*)&xv[0] = *(const float4*)&xs[kk][tm*8];
      *(float4*)&xv[4] = *(const float4*)&xs[kk][tm*8+4];
      #pragma unroll
      for (int j5=0;j5<5;++j5) wv[j5] = wsm[kk][tj + j5*16];
      #pragma unroll
      for (int i=0;i<8;++i)
        #pragma unroll
        for (int j5=0;j5<5;++j5)
          acc[i][j5] = fmaf(xv[i], wv[j5], acc[i][j5]);
    }
  }
  float* pb = part + (size_t)ks*prows*80;
  #pragma unroll
  for (int i=0;i<8;++i){
    int m = m0 + tm*8 + i;
    #pragma unroll
    for (int j5=0;j5<5;++j5)
      pb[(size_t)m*80 + tj + j5*16] = acc[i][j5];
  }
}

// ---------------- reduce partials + layer0 biases (big path; scale 1/256) ----------------
__global__ __launch_bounds__(256) void greduce(
    const float* __restrict__ part,
    const void* __restrict__ bih, const void* __restrict__ bhh,
    float* __restrict__ G, int KS, const int* __restrict__ flag, float scale)
{
  const int isbf = *flag;
  int idx = blockIdx.x*256 + threadIdx.x;
  if (idx >= 2048*80) return;
  int j = idx % 80;
  float s = 0.f;
  for (int k=0;k<KS;++k) s += part[(size_t)k*2048*80 + idx];
  G[idx] = fmaf(s, scale, ldw(bih, j, isbf) + ldw(bhh, j, isbf));
}

// ---------------- reduce chunk partials (compact path) ----------------
template<int CH>
__global__ __launch_bounds__(256) void greduce_chunk(
    const float* __restrict__ part,
    const void* __restrict__ bih, const void* __restrict__ bhh,
    float* __restrict__ G, int KS, const int* __restrict__ flag, int lc)
{
  const int isbf = *flag;
  int idx = blockIdx.x*256 + threadIdx.x;
  if (idx >= B_*CH*80) return;
  int j = idx % 80;
  int rc = idx / 80;
  int b = rc / CH, il = rc % CH;
  float s = ldw(bih, j, isbf) + ldw(bhh, j, isbf);
  for (int k=0;k<KS;++k) s += part[(size_t)k*B_*CH*80 + idx];
  G[((size_t)b*L_ + lc*CH + il)*80 + j] = s;
}

// ---------------- pipelined single-wave 2-layer LSTM, readlane broadcasts ----------------
// 1 wave/batch. Half A (lanes 0-31): layer0 step i; half B (lanes 32-63):
// layer1 step i-1 (skewed pipeline). Zero DS ops in the loop; h broadcast via
// v_readlane at constant lanes. __launch_bounds__(64,1): ONE wave/EU minimum
// -> full 512-VGPR budget so wA/wB (160 floats/lane) stay register-resident
// (at (64) default the allocator capped at 112 VGPRs -> scratch spills, ~2000
// cyc/step reload penalty — the round-14 bottleneck).
__global__ __launch_bounds__(64, 1) void lstm2_pipe(
    const float* __restrict__ G0,
    const void* __restrict__ whh0,
    const void* __restrict__ wih1,
    const void* __restrict__ whh1,
    const void* __restrict__ bih1,
    const void* __restrict__ bhh1,
    float* __restrict__ oseq,
    float* __restrict__ dout,
    const void* __restrict__ linw,
    const void* __restrict__ linb,
    const int* __restrict__ flag)
{
  const int isbf = *flag;
  int b = blockIdx.x; int t = threadIdx.x;
  int half = t >> 5, k0 = t & 31;
  int k = (k0 < 20) ? k0 : 19;          // clamp idle lanes (never read back)
  __shared__ float wsh[3*1600];
  if (isbf){
    const __hip_bfloat16* s0 = (const __hip_bfloat16*)whh0;
    const __hip_bfloat16* s1 = (const __hip_bfloat16*)wih1;
    const __hip_bfloat16* s2 = (const __hip_bfloat16*)whh1;
    for (int i=t;i<1600;i+=64){
      wsh[i] = bf2f(s0[i]); wsh[1600+i] = bf2f(s1[i]); wsh[3200+i] = bf2f(s2[i]);
    }
  } else {
    const float* s0 = (const float*)whh0;
    const float* s1 = (const float*)wih1;
    const float* s2 = (const float*)whh1;
    for (int i=t;i<1600;i+=64){
      wsh[i] = s0[i]; wsh[1600+i] = s1[i]; wsh[3200+i] = s2[i];
    }
  }
  __syncthreads();                       // once, before the scan
  // per-half weight selection: A: wA=Whh0, wB=0 ; B: wA=W1i, wB=W1h
  float wA[4][20], wB[4][20];
  int offA = half ? 1600 : 0;
  #pragma unroll
  for (int q=0;q<4;++q)
    #pragma unroll
    for (int j=0;j<20;++j){
      int row = q*20 + k;
      wA[q][j] = wsh[offA + row*20 + j];
      wB[q][j] = half ? wsh[3200 + row*20 + j] : 0.f;
    }
  float bias1[4];
  #pragma unroll
  for (int q=0;q<4;++q)
    bias1[q] = half ? (ldw(bih1, q*20+k, isbf) + ldw(bhh1, q*20+k, isbf)) : 0.f;
  float lw20[20]; float lb = 0.f;
  const bool fin = (dout != nullptr);
  if (fin){
    #pragma unroll
    for (int j=0;j<20;++j) lw20[j] = ldw(linw, j, isbf);
    lb = ldw(linb, 0, isbf);
  }
  float h0r[20], h1r[20];
  #pragma unroll
  for (int j=0;j<20;++j){ h0r[j]=0.f; h1r[j]=0.f; }
  float c = 0.f;                         // A lanes: c0 ; B lanes: c1
  const float* Gb = G0 + (size_t)b*L_*G4;
  float gc[4], gn[4];
  #pragma unroll
  for (int q=0;q<4;++q) gc[q] = Gb[q*20 + k];
  for (int i=0; i<=L_; ++i){
    int nx = (i+1 < L_) ? (i+1) : (L_-1);
    #pragma unroll
    for (int q=0;q<4;++q) gn[q] = Gb[nx*G4 + q*20 + k];
    // ---- unified gate dots (A: layer0 step i ; B: layer1 step i-1) ----
    float s[4];
    #pragma unroll
    for (int q=0;q<4;++q){
      float v = half ? bias1[q] : gc[q];
      #pragma unroll
      for (int j=0;j<20;++j) v = fmaf(wA[q][j], h0r[j], v);
      #pragma unroll
      for (int j=0;j<20;++j) v = fmaf(wB[q][j], h1r[j], v);
      s[q] = v;
    }
    float ig = sigf(s[0]), fg = sigf(s[1]);
    float gg = tanhf_fast(s[2]), og = sigf(s[3]);
    bool valid = half ? (i > 0) : (i < L_);
    float cn = fmaf(fg, c, ig*gg);
    float hn = og * tanhf_fast(cn);
    c  = valid ? cn : c;
    hn = valid ? hn : 0.f;
    if (oseq && half==1 && k0 < 20 && i >= 1)
      oseq[((size_t)b*L_ + (i-1))*20 + k] = hn;
    // ---- broadcast via readlane: h0 from lanes 0-19, h1 from lanes 32-51 ----
    #pragma unroll
    for (int j=0;j<20;++j) h0r[j] = rdlane(hn, j);
    #pragma unroll
    for (int j=0;j<20;++j) h1r[j] = rdlane(hn, 32+j);
    if (fin && i >= 1){
      float p = lb;
      #pragma unroll
      for (int j=0;j<20;++j){
        float h = h1r[j];
        float wv = (h >= 0.f) ? h : 0.01f*h;   // LeakyReLU(0.01)
        p = fmaf(lw20[j], wv, p);
      }
      if (t == 0) dout[b*L_ + (i-1)] = p;
    }
    #pragma unroll
    for (int q=0;q<4;++q) gc[q] = gn[q];
  }
}

extern "C" void kernel_launch(void* const* d_in, const int* in_sizes, int n_in,
                              void* d_out, int out_size, void* d_ws, size_t ws_size,
                              hipStream_t stream)
{
  (void)out_size;
  auto P = [&](int i){ return (const void*)d_in[i]; };
  float* dout = (float*)d_out;

  static const int EXP[31] = {40960,1280,64,512,8,
    2020720,1600,80,80,1600,1600,80,80,
    673600,1600,80,80,1600,1600,80,80,
    673600,1600,80,80,1600,1600,80,80,
    20,1};
  int bad = (n_in == 31) ? -1 : 99;
  if (bad < 0) for (int i=0;i<31;++i) if (in_sizes[i] != EXP[i]){ bad = i; break; }
  if (bad >= 0){
    fill_k<<<dim3(8), dim3(256), 0, stream>>>(dout, 1000.f + (float)bad);
    return;
  }

  constexpr int CH = 16, NCH = L_/CH;
  const int S1 = 25259, S2 = 8420;
  const int nT1 = (S1+31)/32, nT2 = (S2+31)/32;   // 790, 264
  const int KP1 = nT1*32, KP2 = nT2*32;           // 25280, 8448
  const int SP1 = 25280, SP2 = 8420;

  float* ws = (float*)d_ws;
  size_t off = 0;
  auto alloc = [&](size_t n){ float* p = ws + off; off += (n+3)&~(size_t)3; return p; };
  float* a    = alloc(2048*29);
  float* o1   = alloc(2048*20);
  float* o2   = alloc(2048*20);
  float* mu   = alloc(KP1);
  float* inv  = alloc(KP1);
  float* psum = alloc((size_t)B_*S1);
  float* psq  = alloc((size_t)B_*S1);
  float* G    = alloc(2048*80);
  int*   flag = (int*)alloc(64);

  const bool big     = ws_size >= (size_t)234*1000*1000;
  const bool compact = ws_size >= (size_t)58*1000*1000;
  if (!big && !compact){
    float mb = (float)(ws_size / (1024.0*1024.0));
    fill_k<<<dim3(8), dim3(256), 0, stream>>>(dout, 4000.f + mb);
    return;
  }

  detect_k<<<dim3(1), dim3(256), 0, stream>>>(P(1), 1280, flag);
  augment_k<<<dim3(2048), dim3(64), 0, stream>>>(P(0), P(1), P(2), P(3), P(4), a, flag);

  if (big){
    const int KS = 16;
    float* part = alloc((size_t)KS*2048*80);
    float* whif = alloc((size_t)nT1*1280);
    float* wlof = alloc((size_t)nT1*1280);
    float* sigb = alloc((size_t)2048*SP1);
    _Float16* whi = (_Float16*)whif;
    _Float16* wlo = (_Float16*)wlof;
    const int tpc1 = (nT1 + KS-1)/KS;
    const int tpc2 = (nT2 + KS-1)/KS;
    const float sc = 1.f/256.f;

    auto big_stage = [&](const float* x, int S, int KP, int SP, int nT, int tpc,
                         int wih0_i, int bih0_i, int bhh0_i, int whh0_i,
                         int wih1_i, int whh1_i, int bih1_i, int bhh1_i,
                         float* oseq, float* dd, int lw_i, int lb_i, bool c29)
    {
      if (c29) sig_scan<29,64,true><<<dim3(B_*64), dim3(256), 0, stream>>>(x, sigb, psum, psq, SP);
      else     sig_scan<20,32,true><<<dim3(B_*32), dim3(256), 0, stream>>>(x, sigb, psum, psq, SP);
      bn_stats<<<dim3((KP+255)/256), dim3(256), 0, stream>>>(psum, psq, mu, inv, S, KP, 1.f/2048.f);
      wprep_k<<<dim3((nT*320+255)/256), dim3(256), 0, stream>>>(P(wih0_i), whi, wlo, S, nT, flag);
      gemm_mfma<<<dim3(32, KS), dim3(256), 0, stream>>>(sigb, mu, inv, whi, wlo, part, SP, nT, tpc);
      greduce<<<dim3(640), dim3(256), 0, stream>>>(part, P(bih0_i), P(bhh0_i), G, KS, flag, sc);
      lstm2_pipe<<<dim3(B_), dim3(64), 0, stream>>>(G, P(whh0_i), P(wih1_i), P(whh1_i), P(bih1_i), P(bhh1_i),
                                                    oseq, dd,
                                                    lw_i >= 0 ? P(lw_i) : nullptr,
                                                    lb_i >= 0 ? P(lb_i) : nullptr, flag);
    };

    big_stage(a,  S1, KP1, SP1, nT1, tpc1,  5, 7, 8, 6,  9,10,11,12, o1, nullptr, -1, -1, true);
    big_stage(o1, S2, KP2, SP2, nT2, tpc2, 13,15,16,14, 17,18,19,20, o2, nullptr, -1, -1, false);
    big_stage(o2, S2, KP2, SP2, nT2, tpc2, 21,23,24,22, 25,26,27,28, nullptr, dout, 29, 30, false);
  } else {
    float* st3  = alloc((size_t)B_*29*29*29);
    float* st2  = alloc((size_t)B_*29*29);
    float* st1  = alloc((size_t)B_*29);
    float* stx  = alloc((size_t)B_*29);
    const int KSC = 128;
    float* part = alloc((size_t)KSC*B_*CH*80);
    float* chk  = alloc((size_t)B_*CH*S1);
    const int tpc1 = (nT1 + KSC-1)/KSC;
    const int tpc2 = (nT2 + KSC-1)/KSC;
    const int GRED = (B_*CH*80 + 255)/256;

    sig_scan<29,64,false><<<dim3(B_*64), dim3(256), 0, stream>>>(a, nullptr, psum, psq, S1);
    bn_stats<<<dim3((KP1+255)/256), dim3(256), 0, stream>>>(psum, psq, mu, inv, S1, KP1, 1.f/2048.f);
    for (int lc=0; lc<NCH; ++lc){
      sig_chunk<29,16,CH><<<dim3(B_*16), dim3(256), 0, stream>>>(a, chk, st3, st2, st1, stx, lc);
      gemm_bn<<<dim3(2, KSC), dim3(256), 0, stream>>>(chk, mu, inv, P(5), part, S1, tpc1, flag, B_*CH);
      greduce_chunk<CH><<<dim3(GRED), dim3(256), 0, stream>>>(part, P(7), P(8), G, KSC, flag, lc);
    }
    lstm2_pipe<<<dim3(B_), dim3(64), 0, stream>>>(G, P(6), P(9), P(10), P(11), P(12),
                                                  o1, nullptr, nullptr, nullptr, flag);

    sig_scan<20,32,false><<<dim3(B_*32), dim3(256), 0, stream>>>(o1, nullptr, psum, psq, S2);
    bn_stats<<<dim3((KP2+255)/256), dim3(256), 0, stream>>>(psum, psq, mu, inv, S2, KP2, 1.f/2048.f);
    for (int lc=0; lc<NCH; ++lc){
      sig_chunk<20,8,CH><<<dim3(B_*8), dim3(256), 0, stream>>>(o1, chk, st3, st2, st1, stx, lc);
      gemm_bn<<<dim3(2, KSC), dim3(256), 0, stream>>>(chk, mu, inv, P(13), part, S2, tpc2, flag, B_*CH);
      greduce_chunk<CH><<<dim3(GRED), dim3(256), 0, stream>>>(part, P(15), P(16), G, KSC, flag, lc);
    }
    lstm2_pipe<<<dim3(B_), dim3(64), 0, stream>>>(G, P(14), P(17), P(18), P(19), P(20),
                                                  o2, nullptr, nullptr, nullptr, flag);

    sig_scan<20,32,false><<<dim3(B_*32), dim3(256), 0, stream>>>(o2, nullptr, psum, psq, S2);
    bn_stats<<<dim3((KP2+255)/256), dim3(256), 0, stream>>>(psum, psq, mu, inv, S2, KP2, 1.f/2048.f);
    for (int lc=0; lc<NCH; ++lc){
      sig_chunk<20,8,CH><<<dim3(B_*8), dim3(256), 0, stream>>>(o2, chk, st3, st2, st1, stx, lc);
      gemm_bn<<<dim3(2, KSC), dim3(256), 0, stream>>>(chk, mu, inv, P(21), part, S2, tpc2, flag, B_*CH);
      greduce_chunk<CH><<<dim3(GRED), dim3(256), 0, stream>>>(part, P(23), P(24), G, KSC, flag, lc);
    }
    lstm2_pipe<<<dim3(B_), dim3(64), 0, stream>>>(G, P(22), P(25), P(26), P(27), P(28),
                                                  nullptr, dout, P(29), P(30), flag);
  }
}